// Round 1
// baseline (603.843 us; speedup 1.0000x reference)
//
#include <hip/hip_runtime.h>
#include <hip/hip_bf16.h>

typedef unsigned short u16;
typedef unsigned int   u32;
typedef __attribute__((ext_vector_type(4))) float f4v;
typedef __attribute__((ext_vector_type(8))) short s8v;
typedef __attribute__((ext_vector_type(4))) unsigned int u4v;

#define NB   32      // batch
#define NS   256     // src len
#define NT   8       // dec len
#define NH   512     // hidden
#define NENC 512
#define NEMB 256
#define NVOC 50000
#define NVT  51000

__device__ __forceinline__ float bf2f(u16 u){ return __uint_as_float(((u32)u)<<16); }
__device__ __forceinline__ u16 f2bf(float f){
  u32 x = __float_as_uint(f);
  return (u16)((x + 0x7fffu + ((x>>16)&1u)) >> 16);   // RNE
}
__device__ __forceinline__ s8v ld_frag16(const u16* p){
  union{ s8v v; u4v u; } t;
  t.u = *(const u4v*)p;
  return t.v;
}
__device__ __forceinline__ f4v mfma16(s8v a, s8v b, f4v c){
  return __builtin_amdgcn_mfma_f32_16x16x32_bf16(a,b,c,0,0,0);
}
__device__ __forceinline__ float sigm(float x){ return 1.f/(1.f+__expf(-x)); }

// ---------------------------------------------------------------------------
// Transpose+convert: in [K][N] fp32 -> out [N][K] bf16.  32x32 tiles via LDS.
// grid (ceil(N/32), K/32), block 256.
// ---------------------------------------------------------------------------
__global__ __launch_bounds__(256)
void transpose_cvt(const float* __restrict__ in, u16* __restrict__ out,
                   int K, int N)
{
  __shared__ u16 tile[32*40];
  const int n0 = blockIdx.x*32, k0 = blockIdx.y*32;
  const int tid = threadIdx.x;
  { // load 32 k-rows x 32 n-cols, convert, store [k][n] in LDS
    int r = tid>>3, c4 = tid&7;
    int c = n0 + c4*4;
    if (c+4 > N) c = N-4;
    f4v v = *(const f4v*)(in + (size_t)(k0+r)*N + c);
    uint2 p;
    p.x = (u32)f2bf(v.x) | ((u32)f2bf(v.y)<<16);
    p.y = (u32)f2bf(v.z) | ((u32)f2bf(v.w)<<16);
    *(uint2*)&tile[r*40 + c4*4] = p;
  }
  __syncthreads();
  { // write 32 n-rows x 32 k each (uint2 = 4 bf16 per thread)
    int r2 = tid>>3, kc = tid&7;
    int n = n0 + r2;
    if (n < N){
      u16 e[4];
      #pragma unroll
      for (int j=0; j<4; ++j) e[j] = tile[(kc*4+j)*40 + r2];
      *(uint2*)(out + (size_t)n*K + k0 + kc*4) = *(uint2*)e;
    }
  }
}

// ---------------------------------------------------------------------------
// fp32 -> bf16 converter (grid*256*4 elements)
// ---------------------------------------------------------------------------
__global__ __launch_bounds__(256)
void cvt_bf16(const float* __restrict__ src, u16* __restrict__ dst){
  int i = (blockIdx.x*256 + threadIdx.x) * 4;
  f4v v = *(const f4v*)(src + i);
  uint2 p;
  p.x = (u32)f2bf(v.x) | ((u32)f2bf(v.y)<<16);
  p.y = (u32)f2bf(v.z) | ((u32)f2bf(v.w)<<16);
  *(uint2*)(dst + i) = p;
}

// ---------------------------------------------------------------------------
// Tiled bf16-MFMA GEMM, B pre-transposed: C[M,N] = epi(A[M,K] @ Bt[N,K]^T)
//   A: fp32 (inline convert, optional row-gather) or bf16 direct
//   Bt: bf16 [N][K] row-major -> staged with pure 16B copies (no transpose)
//   EPI 0: fp32 store   1: bf16 store of tanh(x+bias[n])
//   EPI 2: fp32 store of exp(x) for n<nlim + atomic per-row sums
//   MXA:  true -> m0 from blockIdx.x (m fastest)
// Block 256 = 4 waves (2x2), wave tile (BM/2)x(BN/2), 16x16x32 MFMA.
// LDS row stride 40 u16 (80B): 16B-aligned b128 frags, ~2-way banks (free).
// ---------------------------------------------------------------------------
template<int BM, int BN, int EPI, bool ABF16, bool AGATHER, bool MXA>
__global__ __launch_bounds__(256)
void gemm_bt(const void* __restrict__ Av, const u16* __restrict__ Bt,
             float* __restrict__ C, const int* __restrict__ a_idx,
             const float* __restrict__ bias, float* __restrict__ rowsum,
             int K, int lda, int ldc, int nlim)
{
  constexpr int LDT = 40;
  __shared__ u16 Al[BM*LDT];
  __shared__ u16 Bl[BN*LDT];
  const int tid  = threadIdx.x;
  const int lane = tid & 63;
  const int wave = tid >> 6;
  const int m0 = (MXA ? blockIdx.x : blockIdx.y) * BM;
  const int n0 = (MXA ? blockIdx.y : blockIdx.x) * BN;
  constexpr int TM = BM/32;
  constexpr int TN = BN/32;
  const int wm = (wave>>1)*(BM/2);
  const int wn = (wave&1)*(BN/2);
  const int q  = lane >> 4;
  const int ln = lane & 15;

  f4v acc[TM][TN];
  #pragma unroll
  for (int im=0; im<TM; ++im)
    #pragma unroll
    for (int in=0; in<TN; ++in) acc[im][in] = 0.f;

  const int KB = K >> 5;
  for (int kb=0; kb<KB; ++kb){
    __syncthreads();
    // ---- stage A tile [BM x 32k] -> Al
    if (ABF16){
      const u16* Ag = (const u16*)Av;
      #pragma unroll
      for (int p=0; p<BM/64; ++p){
        int el = tid + p*256;
        int row = el>>2, ck = el&3;
        *(u4v*)&Al[row*LDT + ck*8] =
            *(const u4v*)(Ag + (size_t)(m0+row)*lda + kb*32 + ck*8);
      }
    } else {
      const float* Ag = (const float*)Av;
      #pragma unroll
      for (int p=0; p<BM/32; ++p){
        int el = tid + p*256;
        int row = el>>3, ck = el&7;
        int grow = AGATHER ? a_idx[m0+row] : (m0+row);
        f4v v = *(const f4v*)(Ag + (size_t)grow*lda + kb*32 + ck*4);
        uint2 pk;
        pk.x = (u32)f2bf(v.x) | ((u32)f2bf(v.y)<<16);
        pk.y = (u32)f2bf(v.z) | ((u32)f2bf(v.w)<<16);
        *(uint2*)&Al[row*LDT + ck*4] = pk;
      }
    }
    // ---- stage B tile [BN rows x 32k] -> Bl (straight 16B copies)
    #pragma unroll
    for (int p=0; p<BN/64; ++p){
      int el = tid + p*256;
      int row = el>>2, ck = el&3;
      int nr = n0 + row; if (nr >= nlim) nr = nlim-1;
      *(u4v*)&Bl[row*LDT + ck*8] =
          *(const u4v*)(Bt + (size_t)nr*K + kb*32 + ck*8);
    }
    __syncthreads();
    // ---- fragments + MFMA
    s8v af[TM], bfr[TN];
    #pragma unroll
    for (int im=0; im<TM; ++im)
      af[im] = ld_frag16(&Al[(wm+im*16+ln)*LDT + q*8]);
    #pragma unroll
    for (int in=0; in<TN; ++in)
      bfr[in] = ld_frag16(&Bl[(wn+in*16+ln)*LDT + q*8]);
    #pragma unroll
    for (int im=0; im<TM; ++im)
      #pragma unroll
      for (int in=0; in<TN; ++in)
        acc[im][in] = mfma16(af[im], bfr[in], acc[im][in]);
  }

  // ---- epilogue. C/D layout: col = lane&15, row = (lane>>4)*4 + reg
  #pragma unroll
  for (int im=0; im<TM; ++im){
    const int rbase = m0 + wm + im*16 + q*4;
    float rs[4] = {0.f,0.f,0.f,0.f};
    #pragma unroll
    for (int in=0; in<TN; ++in){
      const int col = n0 + wn + in*16 + ln;
      if (EPI == 0){
        #pragma unroll
        for (int r=0; r<4; ++r)
          C[(size_t)(rbase+r)*ldc + col] = acc[im][in][r];
      } else if (EPI == 1){
        float bb = bias[col];
        u16* Cb = (u16*)C;
        #pragma unroll
        for (int r=0; r<4; ++r)
          Cb[(size_t)(rbase+r)*ldc + col] = f2bf(tanhf(acc[im][in][r] + bb));
      } else {
        bool ok = col < nlim;
        #pragma unroll
        for (int r=0; r<4; ++r){
          float e = ok ? __expf(acc[im][in][r]) : 0.f;
          rs[r] += e;
          if (ok) C[(size_t)(rbase+r)*ldc + col] = e;
        }
      }
    }
    if (EPI == 2){
      #pragma unroll
      for (int off=1; off<16; off<<=1){
        rs[0] += __shfl_xor(rs[0], off, 64);
        rs[1] += __shfl_xor(rs[1], off, 64);
        rs[2] += __shfl_xor(rs[2], off, 64);
        rs[3] += __shfl_xor(rs[3], off, 64);
      }
      if (ln == 0){
        #pragma unroll
        for (int r=0; r<4; ++r) atomicAdd(&rowsum[rbase+r], rs[r]);
      }
    }
  }
}

// ---------------------------------------------------------------------------
// One LSTM step. grid 32 (j-slices of 16), block 256 = 4 waves (one per gate).
// Fragments load DIRECTLY from global (wrT bf16 [2048][512], h bf16 [32][512])
// — no LDS / no barrier in the K-loop. Gate-combine via one LDS exchange.
// ---------------------------------------------------------------------------
__global__ __launch_bounds__(256)
void lstm_step2(const u16* __restrict__ wrT, const float* __restrict__ xk,
                const float* __restrict__ bias, const u16* __restrict__ hb_in,
                u16* __restrict__ hb_out, float* __restrict__ c_cur,
                float* __restrict__ hidden, float* __restrict__ out_h,
                float* __restrict__ out_c, int t)
{
  const int tid = threadIdx.x, lane = tid & 63, g = tid >> 6;
  const int q = lane >> 4, ln = lane & 15;
  const int j0 = blockIdx.x * 16;

  f4v acc0 = 0.f, acc1 = 0.f;
  const u16* bp = wrT + (size_t)(g*NH + j0 + ln)*NH;
  const u16* a0 = hb_in + (size_t)ln*NH;
  const u16* a1 = hb_in + (size_t)(16+ln)*NH;
  #pragma unroll 4
  for (int kb=0; kb<16; ++kb){
    s8v bf  = ld_frag16(bp + kb*32 + q*8);
    s8v af0 = ld_frag16(a0 + kb*32 + q*8);
    s8v af1 = ld_frag16(a1 + kb*32 + q*8);
    acc0 = mfma16(af0, bf, acc0);
    acc1 = mfma16(af1, bf, acc1);
  }

  __shared__ float zs[4][32][17];
  #pragma unroll
  for (int r=0; r<4; ++r){
    zs[g][q*4+r][ln]    = acc0[r];
    zs[g][16+q*4+r][ln] = acc1[r];
  }
  __syncthreads();

  #pragma unroll
  for (int pp=0; pp<2; ++pp){
    int pair = tid + pp*256;
    int b = pair >> 4, jj = pair & 15;
    int j = j0 + jj;
    const float* xr = xk + (size_t)(b*NT+t)*2048;
    float zi = zs[0][b][jj] + xr[j]        + bias[j];
    float zf = zs[1][b][jj] + xr[NH+j]     + bias[NH+j];
    float zg = zs[2][b][jj] + xr[2*NH+j]   + bias[2*NH+j];
    float zo = zs[3][b][jj] + xr[3*NH+j]   + bias[3*NH+j];
    float c = sigm(zf)*c_cur[(size_t)b*NH+j] + sigm(zi)*tanhf(zg);
    float h = sigm(zo)*tanhf(c);
    c_cur[(size_t)b*NH+j] = c;
    hb_out[(size_t)b*NH+j] = f2bf(h);
    hidden[(size_t)(b*NT+t)*NH + j] = h;
    if (t == NT-1){ out_h[(size_t)b*NH+j] = h; out_c[(size_t)b*NH+j] = c; }
  }
}

// ---------------------------------------------------------------------------
// Attention: scores = q . enc, masked softmax over s, context; writes
// concat[r][0:512]=context, concat[r][512:1024]=hidden.  grid 32 (b), 1024 thr.
// ---------------------------------------------------------------------------
__global__ __launch_bounds__(1024)
void attn_ctx(const float* __restrict__ q, const float* __restrict__ enc,
              const int* __restrict__ enc_len, const float* __restrict__ hidden,
              float* __restrict__ concat)
{
  const int b = blockIdx.x;
  __shared__ float qs[NT][NENC];
  __shared__ float at[NT][NS];
  __shared__ float cred[NT][NENC];
  const int tid = threadIdx.x;
  for (int i=tid; i<NT*NENC; i+=1024) ((float*)qs)[i] = q[(size_t)b*NT*NENC + i];
  __syncthreads();
  const int len = enc_len[b];
  { // scores: thread = (s, t-pair)
    int s = tid & 255, tg = (tid >> 8) * 2;
    const float* er = enc + ((size_t)(b*NS+s))*NENC;
    float s0 = 0.f, s1 = 0.f;
    for (int e=0; e<NENC; e+=4){
      f4v v = *(const f4v*)(er+e);
      s0 += v.x*qs[tg][e]   + v.y*qs[tg][e+1]   + v.z*qs[tg][e+2]   + v.w*qs[tg][e+3];
      s1 += v.x*qs[tg+1][e] + v.y*qs[tg+1][e+1] + v.z*qs[tg+1][e+2] + v.w*qs[tg+1][e+3];
    }
    bool m = s < len;
    at[tg][s]   = m ? s0 : -3.0e38f;
    at[tg+1][s] = m ? s1 : -3.0e38f;
  }
  __syncthreads();
  { // softmax: wave w handles t=w
    int wave = tid >> 6, lane = tid & 63;
    if (wave < NT){
      float v[4]; float mx = -3.0e38f;
      #pragma unroll
      for (int i=0;i<4;++i){ v[i] = at[wave][lane+64*i]; mx = fmaxf(mx, v[i]); }
      #pragma unroll
      for (int off=1; off<64; off<<=1) mx = fmaxf(mx, __shfl_xor(mx, off, 64));
      float sum = 0.f;
      #pragma unroll
      for (int i=0;i<4;++i){ v[i] = __expf(v[i]-mx); sum += v[i]; }
      #pragma unroll
      for (int off=1; off<64; off<<=1) sum += __shfl_xor(sum, off, 64);
      float inv = 1.f/sum;
      #pragma unroll
      for (int i=0;i<4;++i) at[wave][lane+64*i] = v[i]*inv;
    }
  }
  __syncthreads();
  { // context: thread = (e, s-half)
    int e = tid & 511, sh = tid >> 9;
    float cx[NT];
    #pragma unroll
    for (int t=0;t<NT;++t) cx[t] = 0.f;
    for (int si=0; si<128; ++si){
      int s = sh*128 + si;
      float v = enc[((size_t)(b*NS+s))*NENC + e];
      #pragma unroll
      for (int t=0;t<NT;++t) cx[t] += at[t][s]*v;
    }
    if (sh == 1){
      #pragma unroll
      for (int t=0;t<NT;++t) cred[t][e] = cx[t];
    }
    __syncthreads();
    if (sh == 0){
      #pragma unroll
      for (int t=0;t<NT;++t)
        concat[(size_t)(b*NT+t)*1024 + e] = cx[t] + cred[t][e];
    } else {
      #pragma unroll
      for (int t=0;t<NT;++t)
        concat[(size_t)(b*NT+t)*1024 + 512 + e] = hidden[(size_t)(b*NT+t)*NH + e];
    }
  }
}

// ---------------------------------------------------------------------------
// OOV region fill: total[r][50000:51000] = 1e-10
// ---------------------------------------------------------------------------
__global__ __launch_bounds__(256)
void oov_fill(float* __restrict__ outp){
  float* p = outp + (size_t)blockIdx.x*NVT + NVOC;
  for (int i=threadIdx.x; i<1000; i+=256) p[i] = 1e-10f;
}

// ---------------------------------------------------------------------------
// cs = exp(attn_out @ copy_k^T) with mask; scatter-add into extended vocab
// + rowsum atomics.  MFMA 16x16x32, M=8 padded to 16. grid 128 = (b, sblk).
// ---------------------------------------------------------------------------
__global__ __launch_bounds__(256)
void cs_scatter(const u16* __restrict__ attn_bf, const u16* __restrict__ copy_k,
                const int* __restrict__ enc_x, const int* __restrict__ enc_len,
                float* __restrict__ outp, float* __restrict__ rowsum)
{
  const int b  = blockIdx.x >> 2;
  const int sb = blockIdx.x & 3;
  __shared__ u16 Al[16*520];
  const int tid = threadIdx.x;
  for (int i=tid; i<16*64; i+=256){      // 1024 chunks of 8 shorts
    int row = i >> 6, ck = i & 63;
    uint2 v0 = {0u,0u}, v1 = {0u,0u};
    if (row < NT){
      const u16* s = attn_bf + ((size_t)(b*NT+row))*NH + ck*8;
      v0 = *(const uint2*)s; v1 = *(const uint2*)(s+4);
    }
    u16* d = &Al[row*520 + ck*8];
    *(uint2*)d = v0; *(uint2*)(d+4) = v1;
  }
  __syncthreads();
  const int wave = tid >> 6, lane = tid & 63;
  const int q = lane >> 4, ln = lane & 15;
  const int s0 = sb*64 + wave*16;
  f4v acc = 0.f;
  const u16* Bg = copy_k + ((size_t)(b*NS + s0 + ln))*NH;
  for (int kb=0; kb<16; ++kb){
    s8v a  = ld_frag16(&Al[ln*520 + kb*32 + q*8]);
    s8v bb = ld_frag16(Bg + kb*32 + q*8);
    acc = mfma16(a, bb, acc);
  }
  const int s = s0 + ln;
  const int len = enc_len[b];
  const int vidx = enc_x[b*NS + s];
  const bool valid = (s < len);
  float rs[4];
  #pragma unroll
  for (int r=0; r<4; ++r){
    int t = q*4 + r;
    float e = (valid && t < NT) ? __expf(acc[r]) : 0.f;
    rs[r] = e;
    if (e != 0.f) atomicAdd(&outp[(size_t)(b*NT+t)*NVT + vidx], e);
  }
  #pragma unroll
  for (int off=1; off<16; off<<=1){
    rs[0] += __shfl_xor(rs[0], off, 64);
    rs[1] += __shfl_xor(rs[1], off, 64);
    rs[2] += __shfl_xor(rs[2], off, 64);
    rs[3] += __shfl_xor(rs[3], off, 64);
  }
  if (ln == 0){
    #pragma unroll
    for (int r=0; r<4; ++r){
      int t = q*4 + r;
      if (t < NT) atomicAdd(&rowsum[b*NT+t], rs[r]);
    }
  }
}

// ---------------------------------------------------------------------------
// rowsum -> log(rowsum + 1000*1e-10) in place (256 rows)
// ---------------------------------------------------------------------------
__global__ void log_rowsum(float* rowsum){
  int i = threadIdx.x;
  rowsum[i] = __logf(rowsum[i] + 1e-7f);
}

// ---------------------------------------------------------------------------
// out = log(total) - logsum[row]; 2D grid (f4-chunk, row)
// ---------------------------------------------------------------------------
__global__ __launch_bounds__(256)
void norm_log(float* __restrict__ outp, const float* __restrict__ logsum){
  const int i4 = blockIdx.x*256 + threadIdx.x;   // 0..12749 per row
  if (i4 >= 12750) return;
  const int r = blockIdx.y;
  const float ls = logsum[r];
  float* p = outp + (size_t)r*NVT + i4*4;
  f4v v = *(const f4v*)p;
  v.x = __logf(v.x) - ls;
  v.y = __logf(v.y) - ls;
  v.z = __logf(v.z) - ls;
  v.w = __logf(v.w) - ls;
  *(f4v*)p = v;
}

// ---------------------------------------------------------------------------
extern "C" void kernel_launch(void* const* d_in, const int* in_sizes, int n_in,
                              void* d_out, int out_size, void* d_ws, size_t ws_size,
                              hipStream_t stream)
{
  (void)in_sizes; (void)n_in; (void)out_size; (void)ws_size;
  const int*   dec_x      = (const int*)  d_in[0];
  const int*   enc_x      = (const int*)  d_in[1];
  const int*   enc_len    = (const int*)  d_in[2];
  const float* enc_output = (const float*)d_in[3];
  const float* enc_h      = (const float*)d_in[4];
  const float* enc_c      = (const float*)d_in[5];
  const float* embedding  = (const float*)d_in[8];
  const float* lstm_k     = (const float*)d_in[9];
  const float* lstm_r     = (const float*)d_in[10];
  const float* lstm_b     = (const float*)d_in[11];
  const float* attn_w     = (const float*)d_in[12];
  const float* out_w      = (const float*)d_in[13];
  const float* out_b      = (const float*)d_in[14];
  const float* gen_w      = (const float*)d_in[15];
  const float* copy_w     = (const float*)d_in[16];
  const float* copy_b     = (const float*)d_in[17];

  float* outp  = (float*)d_out;
  float* out_h = outp + (size_t)NB*NT*NVT;       // 13,056,000
  float* out_c = out_h + NB*NH;

  char* ws = (char*)d_ws;
  u16*   genT    = (u16*)ws;    ws += (size_t)NVOC*NH*2;      // 51.2 MB
  u16*   wrT     = (u16*)ws;    ws += (size_t)2048*NH*2;      // 2 MB
  u16*   lstmkT  = (u16*)ws;    ws += (size_t)2048*NEMB*2;    // 1 MB
  u16*   attnT   = (u16*)ws;    ws += (size_t)NENC*NH*2;      // 512 KB
  u16*   outT    = (u16*)ws;    ws += (size_t)NH*1024*2;      // 1 MB
  u16*   copyT   = (u16*)ws;    ws += (size_t)NH*NENC*2;      // 512 KB
  float* xk      = (float*)ws;  ws += (size_t)NB*NT*2048*4;   // 2 MB
  u16*   hb0     = (u16*)ws;    ws += (size_t)NB*NH*2;
  u16*   hb1     = (u16*)ws;    ws += (size_t)NB*NH*2;
  float* c_cur   = (float*)ws;  ws += (size_t)NB*NH*4;
  float* hidden  = (float*)ws;  ws += (size_t)NB*NT*NH*4;     // 512 KB
  float* qbuf    = (float*)ws;  ws += (size_t)NB*NT*NENC*4;   // 512 KB
  float* concat  = (float*)ws;  ws += (size_t)NB*NT*1024*4;   // 1 MB
  u16*   attn_bf = (u16*)ws;    ws += (size_t)NB*NT*NH*2;     // 256 KB
  u16*   copy_k  = (u16*)ws;    ws += (size_t)NB*NS*NH*2;     // 8 MB
  float* rowsum  = (float*)ws;  ws += NB*NT*4;

  hipMemsetAsync(rowsum, 0, NB*NT*4, stream);

  // ---- one-time layout conversions (bf16, [N][K])
  transpose_cvt<<<dim3(1563,16),256,0,stream>>>(gen_w,  genT,   NH,  NVOC);
  transpose_cvt<<<dim3(64,16), 256,0,stream>>>(lstm_r, wrT,    NH,  2048);
  transpose_cvt<<<dim3(64,8),  256,0,stream>>>(lstm_k, lstmkT, NEMB,2048);
  transpose_cvt<<<dim3(16,16), 256,0,stream>>>(attn_w, attnT,  NH,  NENC);
  transpose_cvt<<<dim3(16,32), 256,0,stream>>>(out_w,  outT,   1024,NH);
  transpose_cvt<<<dim3(16,16), 256,0,stream>>>(copy_w, copyT,  NENC,NH);
  cvt_bf16<<<16,256,0,stream>>>(enc_h, hb0);
  hipMemcpyAsync(c_cur, enc_c, NB*NH*4, hipMemcpyDeviceToDevice, stream);

  // copy_k = tanh(enc_output @ copy_w + copy_b) -> bf16 (M=8192, K=512, N=512)
  gemm_bt<128,128,1,false,false,false><<<dim3(4,64),256,0,stream>>>(
      enc_output, copyT, (float*)copy_k, nullptr, copy_b, nullptr, NENC, NENC, NH, NH);

  // xk = embedding[dec_x] @ lstm_k   (M=256, K=256, N=2048)
  gemm_bt<64,64,0,false,true,true><<<dim3(4,32),256,0,stream>>>(
      embedding, lstmkT, xk, dec_x, nullptr, nullptr, NEMB, NEMB, 2048, 2048);

  u16* hb[2] = {hb0, hb1};
  for (int t=0; t<NT; ++t)
    lstm_step2<<<32,256,0,stream>>>(wrT, xk, lstm_b, hb[t&1], hb[(t+1)&1],
                                    c_cur, hidden, out_h, out_c, t);

  // q = hidden @ attn_w  (M=256, K=512, N=512)
  gemm_bt<64,64,0,false,false,true><<<dim3(4,8),256,0,stream>>>(
      hidden, attnT, qbuf, nullptr, nullptr, nullptr, NH, NH, NENC, NENC);

  attn_ctx<<<32,1024,0,stream>>>(qbuf, enc_output, enc_len, hidden, concat);

  // attn_out = tanh(concat @ out_w + out_b) -> bf16  (M=256, K=1024, N=512)
  gemm_bt<64,64,1,false,false,true><<<dim3(4,8),256,0,stream>>>(
      concat, outT, (float*)attn_bf, nullptr, out_b, nullptr, 1024, 1024, NH, NH);

  // gen = exp(attn_out @ gen_w) -> out + row sums (M=256, K=512, N=50000)
  gemm_bt<128,128,2,true,false,true><<<dim3(2,391),256,0,stream>>>(
      attn_bf, genT, outp, nullptr, nullptr, rowsum, NH, NH, NVT, NVOC);

  oov_fill<<<NB*NT,256,0,stream>>>(outp);
  cs_scatter<<<128,256,0,stream>>>(attn_bf, copy_k, enc_x, enc_len, outp, rowsum);
  log_rowsum<<<1,NB*NT,0,stream>>>(rowsum);
  norm_log<<<dim3(50,NB*NT),256,0,stream>>>(outp, rowsum);
}

// Round 2
// 571.175 us; speedup vs baseline: 1.0572x; 1.0572x over previous
//
#include <hip/hip_runtime.h>
#include <hip/hip_bf16.h>

typedef unsigned short u16;
typedef unsigned int   u32;
typedef __attribute__((ext_vector_type(4))) float f4v;
typedef __attribute__((ext_vector_type(8))) short s8v;
typedef __attribute__((ext_vector_type(4))) unsigned int u4v;

#define NB   32      // batch
#define NS   256     // src len
#define NT   8       // dec len
#define NH   512     // hidden
#define NENC 512
#define NEMB 256
#define NVOC 50000
#define NVT  51000

__device__ __forceinline__ float bf2f(u16 u){ return __uint_as_float(((u32)u)<<16); }
__device__ __forceinline__ u16 f2bf(float f){
  u32 x = __float_as_uint(f);
  return (u16)((x + 0x7fffu + ((x>>16)&1u)) >> 16);   // RNE
}
__device__ __forceinline__ s8v ld_frag16(const u16* p){
  union{ s8v v; u4v u; } t;
  t.u = *(const u4v*)p;
  return t.v;
}
__device__ __forceinline__ f4v mfma16(s8v a, s8v b, f4v c){
  return __builtin_amdgcn_mfma_f32_16x16x32_bf16(a,b,c,0,0,0);
}
__device__ __forceinline__ float sigm(float x){ return 1.f/(1.f+__expf(-x)); }

// ---------------------------------------------------------------------------
// Transpose+convert: in [K][N] fp32 -> out [N][K] bf16.  32x32 tiles via LDS.
// grid (ceil(N/32), K/32), block 256.
// ---------------------------------------------------------------------------
__global__ __launch_bounds__(256)
void transpose_cvt(const float* __restrict__ in, u16* __restrict__ out,
                   int K, int N)
{
  __shared__ u16 tile[32*40];
  const int n0 = blockIdx.x*32, k0 = blockIdx.y*32;
  const int tid = threadIdx.x;
  { // load 32 k-rows x 32 n-cols, convert, store [k][n] in LDS
    int r = tid>>3, c4 = tid&7;
    int c = n0 + c4*4;
    if (c+4 > N) c = N-4;
    f4v v = *(const f4v*)(in + (size_t)(k0+r)*N + c);
    uint2 p;
    p.x = (u32)f2bf(v.x) | ((u32)f2bf(v.y)<<16);
    p.y = (u32)f2bf(v.z) | ((u32)f2bf(v.w)<<16);
    *(uint2*)&tile[r*40 + c4*4] = p;
  }
  __syncthreads();
  { // write 32 n-rows x 32 k each (uint2 = 4 bf16 per thread)
    int r2 = tid>>3, kc = tid&7;
    int n = n0 + r2;
    if (n < N){
      u16 e[4];
      #pragma unroll
      for (int j=0; j<4; ++j) e[j] = tile[(kc*4+j)*40 + r2];
      *(uint2*)(out + (size_t)n*K + k0 + kc*4) = *(uint2*)e;
    }
  }
}

// ---------------------------------------------------------------------------
// fp32 -> bf16 converter (grid*256*4 elements)
// ---------------------------------------------------------------------------
__global__ __launch_bounds__(256)
void cvt_bf16(const float* __restrict__ src, u16* __restrict__ dst){
  int i = (blockIdx.x*256 + threadIdx.x) * 4;
  f4v v = *(const f4v*)(src + i);
  uint2 p;
  p.x = (u32)f2bf(v.x) | ((u32)f2bf(v.y)<<16);
  p.y = (u32)f2bf(v.z) | ((u32)f2bf(v.w)<<16);
  *(uint2*)(dst + i) = p;
}

// ---------------------------------------------------------------------------
// Tiled bf16-MFMA GEMM, B pre-transposed: C[M,N] = epi(A[M,K] @ Bt[N,K]^T)
//   A: fp32 (inline convert, optional row-gather) or bf16 direct
//   Bt: bf16 [N][K] row-major
//   EPI 0: fp32 store   1: bf16 store of tanh(x+bias[n])
//   EPI 2: fp32 store of exp(x) for n<nlim + atomic per-row sums
//   MXA:  true -> m0 from blockIdx.x (m fastest)
// Pipelined K-loop: double-buffered LDS, reg-staged prefetch of tile k+1
// issued BEFORE the (single) barrier — register-destined loads stay in
// flight across s_barrier, so HBM latency hides under MFMA of tile k.
// Block 256 = 4 waves (2x2), wave tile (BM/2)x(BN/2), 16x16x32 MFMA.
// LDS row stride 40 u16 (80B): 16B-aligned b128 frags, ~2-way banks (free).
// ---------------------------------------------------------------------------
template<int BM, int BN, int EPI, bool ABF16, bool AGATHER, bool MXA>
__global__ __launch_bounds__(256)
void gemm_bt(const void* __restrict__ Av, const u16* __restrict__ Bt,
             float* __restrict__ C, const int* __restrict__ a_idx,
             const float* __restrict__ bias, float* __restrict__ rowsum,
             int K, int lda, int ldc, int nlim)
{
  constexpr int LDT = 40;
  constexpr int PA  = ABF16 ? BM/64 : BM/32;   // staging loads/thread for A
  constexpr int PB  = BN/64;                   // staging loads/thread for B
  __shared__ u16 Al[2][BM*LDT];
  __shared__ u16 Bl[2][BN*LDT];
  const int tid  = threadIdx.x;
  const int lane = tid & 63;
  const int wave = tid >> 6;
  const int m0 = (MXA ? blockIdx.x : blockIdx.y) * BM;
  const int n0 = (MXA ? blockIdx.y : blockIdx.x) * BN;
  constexpr int TM = BM/32;
  constexpr int TN = BN/32;
  const int wm = (wave>>1)*(BM/2);
  const int wn = (wave&1)*(BN/2);
  const int q  = lane >> 4;
  const int ln = lane & 15;

  // ---- per-thread staging coordinates (invariant over kb)
  const u16*  aS16[PA];
  const float* aS32[PA];
  int aOff[PA];
  if (ABF16){
    const u16* Ag = (const u16*)Av;
    #pragma unroll
    for (int p=0; p<PA; ++p){
      int el = tid + p*256, row = el>>2, ck = el&3;
      aS16[p] = Ag + (size_t)(m0+row)*lda + ck*8;
      aS32[p] = nullptr;
      aOff[p] = row*LDT + ck*8;
    }
  } else {
    const float* Ag = (const float*)Av;
    #pragma unroll
    for (int p=0; p<PA; ++p){
      int el = tid + p*256, row = el>>3, ck = el&7;
      int grow = AGATHER ? a_idx[m0+row] : (m0+row);
      aS32[p] = Ag + (size_t)grow*lda + ck*4;
      aS16[p] = nullptr;
      aOff[p] = row*LDT + ck*4;
    }
  }
  const u16* bS[PB];
  int bOff[PB];
  #pragma unroll
  for (int p=0; p<PB; ++p){
    int el = tid + p*256, row = el>>2, ck = el&3;
    int nr = n0 + row; if (nr >= nlim) nr = nlim-1;
    bS[p]   = Bt + (size_t)nr*K + ck*8;
    bOff[p] = row*LDT + ck*8;
  }

  f4v acc[TM][TN];
  #pragma unroll
  for (int im=0; im<TM; ++im)
    #pragma unroll
    for (int in=0; in<TN; ++in) acc[im][in] = 0.f;

  // ---- prologue: load tile 0 into regs
  u4v aR[PA]; f4v aF[PA]; u4v bR[PB];
  if (ABF16){
    #pragma unroll
    for (int p=0; p<PA; ++p) aR[p] = *(const u4v*)(aS16[p]);
  } else {
    #pragma unroll
    for (int p=0; p<PA; ++p) aF[p] = *(const f4v*)(aS32[p]);
  }
  #pragma unroll
  for (int p=0; p<PB; ++p) bR[p] = *(const u4v*)(bS[p]);

  const int KB = K >> 5;
  int cur = 0;
  for (int kb=0; kb<KB; ++kb){
    // ---- commit regs (tile kb) to LDS[cur]
    if (ABF16){
      #pragma unroll
      for (int p=0; p<PA; ++p) *(u4v*)&Al[cur][aOff[p]] = aR[p];
    } else {
      #pragma unroll
      for (int p=0; p<PA; ++p){
        uint2 pk;
        pk.x = (u32)f2bf(aF[p].x) | ((u32)f2bf(aF[p].y)<<16);
        pk.y = (u32)f2bf(aF[p].z) | ((u32)f2bf(aF[p].w)<<16);
        *(uint2*)&Al[cur][aOff[p]] = pk;
      }
    }
    #pragma unroll
    for (int p=0; p<PB; ++p) *(u4v*)&Bl[cur][bOff[p]] = bR[p];
    // ---- issue prefetch of tile kb+1 into regs (stays in flight past barrier)
    if (kb+1 < KB){
      const int ko = (kb+1)*32;
      if (ABF16){
        #pragma unroll
        for (int p=0; p<PA; ++p) aR[p] = *(const u4v*)(aS16[p] + ko);
      } else {
        #pragma unroll
        for (int p=0; p<PA; ++p) aF[p] = *(const f4v*)(aS32[p] + ko);
      }
      #pragma unroll
      for (int p=0; p<PB; ++p) bR[p] = *(const u4v*)(bS[p] + ko);
    }
    __syncthreads();
    // ---- fragments + MFMA from LDS[cur]
    s8v af[TM], bfr[TN];
    #pragma unroll
    for (int im=0; im<TM; ++im)
      af[im] = ld_frag16(&Al[cur][(wm+im*16+ln)*LDT + q*8]);
    #pragma unroll
    for (int in=0; in<TN; ++in)
      bfr[in] = ld_frag16(&Bl[cur][(wn+in*16+ln)*LDT + q*8]);
    #pragma unroll
    for (int im=0; im<TM; ++im)
      #pragma unroll
      for (int in=0; in<TN; ++in)
        acc[im][in] = mfma16(af[im], bfr[in], acc[im][in]);
    cur ^= 1;
  }

  // ---- epilogue. C/D layout: col = lane&15, row = (lane>>4)*4 + reg
  #pragma unroll
  for (int im=0; im<TM; ++im){
    const int rbase = m0 + wm + im*16 + q*4;
    float rs[4] = {0.f,0.f,0.f,0.f};
    #pragma unroll
    for (int in=0; in<TN; ++in){
      const int col = n0 + wn + in*16 + ln;
      if (EPI == 0){
        #pragma unroll
        for (int r=0; r<4; ++r)
          C[(size_t)(rbase+r)*ldc + col] = acc[im][in][r];
      } else if (EPI == 1){
        float bb = bias[col];
        u16* Cb = (u16*)C;
        #pragma unroll
        for (int r=0; r<4; ++r)
          Cb[(size_t)(rbase+r)*ldc + col] = f2bf(tanhf(acc[im][in][r] + bb));
      } else {
        bool ok = col < nlim;
        #pragma unroll
        for (int r=0; r<4; ++r){
          float e = ok ? __expf(acc[im][in][r]) : 0.f;
          rs[r] += e;
          if (ok) C[(size_t)(rbase+r)*ldc + col] = e;
        }
      }
    }
    if (EPI == 2){
      #pragma unroll
      for (int off=1; off<16; off<<=1){
        rs[0] += __shfl_xor(rs[0], off, 64);
        rs[1] += __shfl_xor(rs[1], off, 64);
        rs[2] += __shfl_xor(rs[2], off, 64);
        rs[3] += __shfl_xor(rs[3], off, 64);
      }
      if (ln == 0){
        #pragma unroll
        for (int r=0; r<4; ++r) atomicAdd(&rowsum[rbase+r], rs[r]);
      }
    }
  }
}

// ---------------------------------------------------------------------------
// One LSTM step. grid 32 (j-slices of 16), block 256 = 4 waves (one per gate).
// Fragments load DIRECTLY from global (wrT bf16 [2048][512], h bf16 [32][512])
// — no LDS / no barrier in the K-loop. Gate-combine via one LDS exchange.
// ---------------------------------------------------------------------------
__global__ __launch_bounds__(256)
void lstm_step2(const u16* __restrict__ wrT, const float* __restrict__ xk,
                const float* __restrict__ bias, const u16* __restrict__ hb_in,
                u16* __restrict__ hb_out, float* __restrict__ c_cur,
                float* __restrict__ hidden, float* __restrict__ out_h,
                float* __restrict__ out_c, int t)
{
  const int tid = threadIdx.x, lane = tid & 63, g = tid >> 6;
  const int q = lane >> 4, ln = lane & 15;
  const int j0 = blockIdx.x * 16;

  f4v acc0 = 0.f, acc1 = 0.f;
  const u16* bp = wrT + (size_t)(g*NH + j0 + ln)*NH;
  const u16* a0 = hb_in + (size_t)ln*NH;
  const u16* a1 = hb_in + (size_t)(16+ln)*NH;
  #pragma unroll 4
  for (int kb=0; kb<16; ++kb){
    s8v bf  = ld_frag16(bp + kb*32 + q*8);
    s8v af0 = ld_frag16(a0 + kb*32 + q*8);
    s8v af1 = ld_frag16(a1 + kb*32 + q*8);
    acc0 = mfma16(af0, bf, acc0);
    acc1 = mfma16(af1, bf, acc1);
  }

  __shared__ float zs[4][32][17];
  #pragma unroll
  for (int r=0; r<4; ++r){
    zs[g][q*4+r][ln]    = acc0[r];
    zs[g][16+q*4+r][ln] = acc1[r];
  }
  __syncthreads();

  #pragma unroll
  for (int pp=0; pp<2; ++pp){
    int pair = tid + pp*256;
    int b = pair >> 4, jj = pair & 15;
    int j = j0 + jj;
    const float* xr = xk + (size_t)(b*NT+t)*2048;
    float zi = zs[0][b][jj] + xr[j]        + bias[j];
    float zf = zs[1][b][jj] + xr[NH+j]     + bias[NH+j];
    float zg = zs[2][b][jj] + xr[2*NH+j]   + bias[2*NH+j];
    float zo = zs[3][b][jj] + xr[3*NH+j]   + bias[3*NH+j];
    float c = sigm(zf)*c_cur[(size_t)b*NH+j] + sigm(zi)*tanhf(zg);
    float h = sigm(zo)*tanhf(c);
    c_cur[(size_t)b*NH+j] = c;
    hb_out[(size_t)b*NH+j] = f2bf(h);
    hidden[(size_t)(b*NT+t)*NH + j] = h;
    if (t == NT-1){ out_h[(size_t)b*NH+j] = h; out_c[(size_t)b*NH+j] = c; }
  }
}

// ---------------------------------------------------------------------------
// Attention: scores = q . enc, masked softmax over s, context; writes
// concat[r][0:512]=context, concat[r][512:1024]=hidden.  grid 32 (b), 1024 thr.
// ---------------------------------------------------------------------------
__global__ __launch_bounds__(1024)
void attn_ctx(const float* __restrict__ q, const float* __restrict__ enc,
              const int* __restrict__ enc_len, const float* __restrict__ hidden,
              float* __restrict__ concat)
{
  const int b = blockIdx.x;
  __shared__ float qs[NT][NENC];
  __shared__ float at[NT][NS];
  __shared__ float cred[NT][NENC];
  const int tid = threadIdx.x;
  for (int i=tid; i<NT*NENC; i+=1024) ((float*)qs)[i] = q[(size_t)b*NT*NENC + i];
  __syncthreads();
  const int len = enc_len[b];
  { // scores: thread = (s, t-pair)
    int s = tid & 255, tg = (tid >> 8) * 2;
    const float* er = enc + ((size_t)(b*NS+s))*NENC;
    float s0 = 0.f, s1 = 0.f;
    for (int e=0; e<NENC; e+=4){
      f4v v = *(const f4v*)(er+e);
      s0 += v.x*qs[tg][e]   + v.y*qs[tg][e+1]   + v.z*qs[tg][e+2]   + v.w*qs[tg][e+3];
      s1 += v.x*qs[tg+1][e] + v.y*qs[tg+1][e+1] + v.z*qs[tg+1][e+2] + v.w*qs[tg+1][e+3];
    }
    bool m = s < len;
    at[tg][s]   = m ? s0 : -3.0e38f;
    at[tg+1][s] = m ? s1 : -3.0e38f;
  }
  __syncthreads();
  { // softmax: wave w handles t=w
    int wave = tid >> 6, lane = tid & 63;
    if (wave < NT){
      float v[4]; float mx = -3.0e38f;
      #pragma unroll
      for (int i=0;i<4;++i){ v[i] = at[wave][lane+64*i]; mx = fmaxf(mx, v[i]); }
      #pragma unroll
      for (int off=1; off<64; off<<=1) mx = fmaxf(mx, __shfl_xor(mx, off, 64));
      float sum = 0.f;
      #pragma unroll
      for (int i=0;i<4;++i){ v[i] = __expf(v[i]-mx); sum += v[i]; }
      #pragma unroll
      for (int off=1; off<64; off<<=1) sum += __shfl_xor(sum, off, 64);
      float inv = 1.f/sum;
      #pragma unroll
      for (int i=0;i<4;++i) at[wave][lane+64*i] = v[i]*inv;
    }
  }
  __syncthreads();
  { // context: thread = (e, s-half)
    int e = tid & 511, sh = tid >> 9;
    float cx[NT];
    #pragma unroll
    for (int t=0;t<NT;++t) cx[t] = 0.f;
    for (int si=0; si<128; ++si){
      int s = sh*128 + si;
      float v = enc[((size_t)(b*NS+s))*NENC + e];
      #pragma unroll
      for (int t=0;t<NT;++t) cx[t] += at[t][s]*v;
    }
    if (sh == 1){
      #pragma unroll
      for (int t=0;t<NT;++t) cred[t][e] = cx[t];
    }
    __syncthreads();
    if (sh == 0){
      #pragma unroll
      for (int t=0;t<NT;++t)
        concat[(size_t)(b*NT+t)*1024 + e] = cx[t] + cred[t][e];
    } else {
      #pragma unroll
      for (int t=0;t<NT;++t)
        concat[(size_t)(b*NT+t)*1024 + 512 + e] = hidden[(size_t)(b*NT+t)*NH + e];
    }
  }
}

// ---------------------------------------------------------------------------
// OOV region fill: total[r][50000:51000] = 1e-10
// ---------------------------------------------------------------------------
__global__ __launch_bounds__(256)
void oov_fill(float* __restrict__ outp){
  float* p = outp + (size_t)blockIdx.x*NVT + NVOC;
  for (int i=threadIdx.x; i<1000; i+=256) p[i] = 1e-10f;
}

// ---------------------------------------------------------------------------
// cs = exp(attn_out @ copy_k^T) with mask; scatter-add into extended vocab
// + rowsum atomics.  MFMA 16x16x32, M=8 padded to 16. grid 128 = (b, sblk).
// ---------------------------------------------------------------------------
__global__ __launch_bounds__(256)
void cs_scatter(const u16* __restrict__ attn_bf, const u16* __restrict__ copy_k,
                const int* __restrict__ enc_x, const int* __restrict__ enc_len,
                float* __restrict__ outp, float* __restrict__ rowsum)
{
  const int b  = blockIdx.x >> 2;
  const int sb = blockIdx.x & 3;
  __shared__ u16 Al[16*520];
  const int tid = threadIdx.x;
  for (int i=tid; i<16*64; i+=256){      // 1024 chunks of 8 shorts
    int row = i >> 6, ck = i & 63;
    uint2 v0 = {0u,0u}, v1 = {0u,0u};
    if (row < NT){
      const u16* s = attn_bf + ((size_t)(b*NT+row))*NH + ck*8;
      v0 = *(const uint2*)s; v1 = *(const uint2*)(s+4);
    }
    u16* d = &Al[row*520 + ck*8];
    *(uint2*)d = v0; *(uint2*)(d+4) = v1;
  }
  __syncthreads();
  const int wave = tid >> 6, lane = tid & 63;
  const int q = lane >> 4, ln = lane & 15;
  const int s0 = sb*64 + wave*16;
  f4v acc = 0.f;
  const u16* Bg = copy_k + ((size_t)(b*NS + s0 + ln))*NH;
  for (int kb=0; kb<16; ++kb){
    s8v a  = ld_frag16(&Al[ln*520 + kb*32 + q*8]);
    s8v bb = ld_frag16(Bg + kb*32 + q*8);
    acc = mfma16(a, bb, acc);
  }
  const int s = s0 + ln;
  const int len = enc_len[b];
  const int vidx = enc_x[b*NS + s];
  const bool valid = (s < len);
  float rs[4];
  #pragma unroll
  for (int r=0; r<4; ++r){
    int t = q*4 + r;
    float e = (valid && t < NT) ? __expf(acc[r]) : 0.f;
    rs[r] = e;
    if (e != 0.f) atomicAdd(&outp[(size_t)(b*NT+t)*NVT + vidx], e);
  }
  #pragma unroll
  for (int off=1; off<16; off<<=1){
    rs[0] += __shfl_xor(rs[0], off, 64);
    rs[1] += __shfl_xor(rs[1], off, 64);
    rs[2] += __shfl_xor(rs[2], off, 64);
    rs[3] += __shfl_xor(rs[3], off, 64);
  }
  if (ln == 0){
    #pragma unroll
    for (int r=0; r<4; ++r){
      int t = q*4 + r;
      if (t < NT) atomicAdd(&rowsum[b*NT+t], rs[r]);
    }
  }
}

// ---------------------------------------------------------------------------
// rowsum -> log(rowsum + 1000*1e-10) in place (256 rows)
// ---------------------------------------------------------------------------
__global__ void log_rowsum(float* rowsum){
  int i = threadIdx.x;
  rowsum[i] = __logf(rowsum[i] + 1e-7f);
}

// ---------------------------------------------------------------------------
// out = log(total) - logsum[row]; 2D grid (f4-chunk, row)
// ---------------------------------------------------------------------------
__global__ __launch_bounds__(256)
void norm_log(float* __restrict__ outp, const float* __restrict__ logsum){
  const int i4 = blockIdx.x*256 + threadIdx.x;   // 0..12749 per row
  if (i4 >= 12750) return;
  const int r = blockIdx.y;
  const float ls = logsum[r];
  float* p = outp + (size_t)r*NVT + i4*4;
  f4v v = *(const f4v*)p;
  v.x = __logf(v.x) - ls;
  v.y = __logf(v.y) - ls;
  v.z = __logf(v.z) - ls;
  v.w = __logf(v.w) - ls;
  *(f4v*)p = v;
}

// ---------------------------------------------------------------------------
extern "C" void kernel_launch(void* const* d_in, const int* in_sizes, int n_in,
                              void* d_out, int out_size, void* d_ws, size_t ws_size,
                              hipStream_t stream)
{
  (void)in_sizes; (void)n_in; (void)out_size; (void)ws_size;
  const int*   dec_x      = (const int*)  d_in[0];
  const int*   enc_x      = (const int*)  d_in[1];
  const int*   enc_len    = (const int*)  d_in[2];
  const float* enc_output = (const float*)d_in[3];
  const float* enc_h      = (const float*)d_in[4];
  const float* enc_c      = (const float*)d_in[5];
  const float* embedding  = (const float*)d_in[8];
  const float* lstm_k     = (const float*)d_in[9];
  const float* lstm_r     = (const float*)d_in[10];
  const float* lstm_b     = (const float*)d_in[11];
  const float* attn_w     = (const float*)d_in[12];
  const float* out_w      = (const float*)d_in[13];
  const float* out_b      = (const float*)d_in[14];
  const float* gen_w      = (const float*)d_in[15];
  const float* copy_w     = (const float*)d_in[16];
  const float* copy_b     = (const float*)d_in[17];

  float* outp  = (float*)d_out;
  float* out_h = outp + (size_t)NB*NT*NVT;       // 13,056,000
  float* out_c = out_h + NB*NH;

  char* ws = (char*)d_ws;
  u16*   genT    = (u16*)ws;    ws += (size_t)NVOC*NH*2;      // 51.2 MB
  u16*   wrT     = (u16*)ws;    ws += (size_t)2048*NH*2;      // 2 MB
  u16*   lstmkT  = (u16*)ws;    ws += (size_t)2048*NEMB*2;    // 1 MB
  u16*   attnT   = (u16*)ws;    ws += (size_t)NENC*NH*2;      // 512 KB
  u16*   outT    = (u16*)ws;    ws += (size_t)NH*1024*2;      // 1 MB
  u16*   copyT   = (u16*)ws;    ws += (size_t)NH*NENC*2;      // 512 KB
  float* xk      = (float*)ws;  ws += (size_t)NB*NT*2048*4;   // 2 MB
  u16*   hb0     = (u16*)ws;    ws += (size_t)NB*NH*2;
  u16*   hb1     = (u16*)ws;    ws += (size_t)NB*NH*2;
  float* c_cur   = (float*)ws;  ws += (size_t)NB*NH*4;
  float* hidden  = (float*)ws;  ws += (size_t)NB*NT*NH*4;     // 512 KB
  float* qbuf    = (float*)ws;  ws += (size_t)NB*NT*NENC*4;   // 512 KB
  float* concat  = (float*)ws;  ws += (size_t)NB*NT*1024*4;   // 1 MB
  u16*   attn_bf = (u16*)ws;    ws += (size_t)NB*NT*NH*2;     // 256 KB
  u16*   copy_k  = (u16*)ws;    ws += (size_t)NB*NS*NH*2;     // 8 MB
  float* rowsum  = (float*)ws;  ws += NB*NT*4;

  hipMemsetAsync(rowsum, 0, NB*NT*4, stream);

  // ---- one-time layout conversions (bf16, [N][K])
  transpose_cvt<<<dim3(1563,16),256,0,stream>>>(gen_w,  genT,   NH,  NVOC);
  transpose_cvt<<<dim3(64,16), 256,0,stream>>>(lstm_r, wrT,    NH,  2048);
  transpose_cvt<<<dim3(64,8),  256,0,stream>>>(lstm_k, lstmkT, NEMB,2048);
  transpose_cvt<<<dim3(16,16), 256,0,stream>>>(attn_w, attnT,  NH,  NENC);
  transpose_cvt<<<dim3(16,32), 256,0,stream>>>(out_w,  outT,   1024,NH);
  transpose_cvt<<<dim3(16,16), 256,0,stream>>>(copy_w, copyT,  NENC,NH);
  cvt_bf16<<<16,256,0,stream>>>(enc_h, hb0);
  hipMemcpyAsync(c_cur, enc_c, NB*NH*4, hipMemcpyDeviceToDevice, stream);

  // copy_k = tanh(enc_output @ copy_w + copy_b) -> bf16 (M=8192, K=512, N=512)
  gemm_bt<64,128,1,false,false,false><<<dim3(4,128),256,0,stream>>>(
      enc_output, copyT, (float*)copy_k, nullptr, copy_b, nullptr, NENC, NENC, NH, NH);

  // xk = embedding[dec_x] @ lstm_k   (M=256, K=256, N=2048)
  gemm_bt<64,64,0,false,true,true><<<dim3(4,32),256,0,stream>>>(
      embedding, lstmkT, xk, dec_x, nullptr, nullptr, NEMB, NEMB, 2048, 2048);

  u16* hb[2] = {hb0, hb1};
  for (int t=0; t<NT; ++t)
    lstm_step2<<<32,256,0,stream>>>(wrT, xk, lstm_b, hb[t&1], hb[(t+1)&1],
                                    c_cur, hidden, out_h, out_c, t);

  // q = hidden @ attn_w  (M=256, K=512, N=512)
  gemm_bt<64,64,0,false,false,true><<<dim3(4,8),256,0,stream>>>(
      hidden, attnT, qbuf, nullptr, nullptr, nullptr, NH, NH, NENC, NENC);

  attn_ctx<<<32,1024,0,stream>>>(qbuf, enc_output, enc_len, hidden, concat);

  // attn_out = tanh(concat @ out_w + out_b) -> bf16  (M=256, K=1024, N=512)
  gemm_bt<64,64,1,false,false,true><<<dim3(4,8),256,0,stream>>>(
      concat, outT, (float*)attn_bf, nullptr, out_b, nullptr, 1024, 1024, NH, NH);

  // gen = exp(attn_out @ gen_w) -> out + row sums (M=256, K=512, N=50000)
  gemm_bt<64,128,2,true,false,true><<<dim3(4,391),256,0,stream>>>(
      attn_bf, genT, outp, nullptr, nullptr, rowsum, NH, NH, NVT, NVOC);

  oov_fill<<<NB*NT,256,0,stream>>>(outp);
  cs_scatter<<<128,256,0,stream>>>(attn_bf, copy_k, enc_x, enc_len, outp, rowsum);
  log_rowsum<<<1,NB*NT,0,stream>>>(rowsum);
  norm_log<<<dim3(50,NB*NT),256,0,stream>>>(outp, rowsum);
}

// Round 4
// 502.553 us; speedup vs baseline: 1.2016x; 1.1365x over previous
//
#include <hip/hip_runtime.h>
#include <hip/hip_bf16.h>

typedef unsigned short u16;
typedef unsigned int   u32;
typedef __attribute__((ext_vector_type(4))) float f4v;
typedef __attribute__((ext_vector_type(8))) short s8v;
typedef __attribute__((ext_vector_type(4))) unsigned int u4v;

#define NB   32      // batch
#define NS   256     // src len
#define NT   8       // dec len
#define NH   512     // hidden
#define NENC 512
#define NEMB 256
#define NVOC 50000
#define NVT  51000

__device__ __forceinline__ float bf2f(u16 u){ return __uint_as_float(((u32)u)<<16); }
__device__ __forceinline__ u16 f2bf(float f){
  u32 x = __float_as_uint(f);
  return (u16)((x + 0x7fffu + ((x>>16)&1u)) >> 16);   // RNE
}
__device__ __forceinline__ s8v ld_frag16(const u16* p){
  union{ s8v v; u4v u; } t;
  t.u = *(const u4v*)p;
  return t.v;
}
__device__ __forceinline__ f4v mfma16(s8v a, s8v b, f4v c){
  return __builtin_amdgcn_mfma_f32_16x16x32_bf16(a,b,c,0,0,0);
}
__device__ __forceinline__ float sigm(float x){ return 1.f/(1.f+__expf(-x)); }

// ---------------------------------------------------------------------------
// Transpose+convert: in [K][N] fp32 -> out [N][K] bf16.  32x32 tiles via LDS.
// grid (ceil(N/32), K/32), block 256.  (small weights only now)
// ---------------------------------------------------------------------------
__global__ __launch_bounds__(256)
void transpose_cvt(const float* __restrict__ in, u16* __restrict__ out,
                   int K, int N)
{
  __shared__ u16 tile[32*40];
  const int n0 = blockIdx.x*32, k0 = blockIdx.y*32;
  const int tid = threadIdx.x;
  {
    int r = tid>>3, c4 = tid&7;
    int c = n0 + c4*4;
    if (c+4 > N) c = N-4;
    f4v v = *(const f4v*)(in + (size_t)(k0+r)*N + c);
    uint2 p;
    p.x = (u32)f2bf(v.x) | ((u32)f2bf(v.y)<<16);
    p.y = (u32)f2bf(v.z) | ((u32)f2bf(v.w)<<16);
    *(uint2*)&tile[r*40 + c4*4] = p;
  }
  __syncthreads();
  {
    int r2 = tid>>3, kc = tid&7;
    int n = n0 + r2;
    if (n < N){
      u16 e[4];
      #pragma unroll
      for (int j=0; j<4; ++j) e[j] = tile[(kc*4+j)*40 + r2];
      *(uint2*)(out + (size_t)n*K + k0 + kc*4) = *(uint2*)e;
    }
  }
}

// ---------------------------------------------------------------------------
// fp32 -> bf16 converter (grid*256*4 elements)
// ---------------------------------------------------------------------------
__global__ __launch_bounds__(256)
void cvt_bf16(const float* __restrict__ src, u16* __restrict__ dst){
  int i = (blockIdx.x*256 + threadIdx.x) * 4;
  f4v v = *(const f4v*)(src + i);
  uint2 p;
  p.x = (u32)f2bf(v.x) | ((u32)f2bf(v.y)<<16);
  p.y = (u32)f2bf(v.z) | ((u32)f2bf(v.w)<<16);
  *(uint2*)(dst + i) = p;
}

// ---------------------------------------------------------------------------
// Tiled bf16-MFMA GEMM, B pre-transposed: C[M,N] = epi(A[M,K] @ Bt[N,K]^T)
// (small/medium GEMMs). Pipelined K-loop: double-buffered LDS, reg-staged
// prefetch of tile k+1 issued BEFORE the barrier.
// ---------------------------------------------------------------------------
template<int BM, int BN, int EPI, bool ABF16, bool AGATHER, bool MXA>
__global__ __launch_bounds__(256)
void gemm_bt(const void* __restrict__ Av, const u16* __restrict__ Bt,
             float* __restrict__ C, const int* __restrict__ a_idx,
             const float* __restrict__ bias, float* __restrict__ rowsum,
             int K, int lda, int ldc, int nlim)
{
  constexpr int LDT = 40;
  constexpr int PA  = ABF16 ? BM/64 : BM/32;
  constexpr int PB  = BN/64;
  __shared__ u16 Al[2][BM*LDT];
  __shared__ u16 Bl[2][BN*LDT];
  const int tid  = threadIdx.x;
  const int lane = tid & 63;
  const int wave = tid >> 6;
  const int m0 = (MXA ? blockIdx.x : blockIdx.y) * BM;
  const int n0 = (MXA ? blockIdx.y : blockIdx.x) * BN;
  constexpr int TM = BM/32;
  constexpr int TN = BN/32;
  const int wm = (wave>>1)*(BM/2);
  const int wn = (wave&1)*(BN/2);
  const int q  = lane >> 4;
  const int ln = lane & 15;

  const u16*  aS16[PA];
  const float* aS32[PA];
  int aOff[PA];
  if (ABF16){
    const u16* Ag = (const u16*)Av;
    #pragma unroll
    for (int p=0; p<PA; ++p){
      int el = tid + p*256, row = el>>2, ck = el&3;
      aS16[p] = Ag + (size_t)(m0+row)*lda + ck*8;
      aS32[p] = nullptr;
      aOff[p] = row*LDT + ck*8;
    }
  } else {
    const float* Ag = (const float*)Av;
    #pragma unroll
    for (int p=0; p<PA; ++p){
      int el = tid + p*256, row = el>>3, ck = el&7;
      int grow = AGATHER ? a_idx[m0+row] : (m0+row);
      aS32[p] = Ag + (size_t)grow*lda + ck*4;
      aS16[p] = nullptr;
      aOff[p] = row*LDT + ck*4;
    }
  }
  const u16* bS[PB];
  int bOff[PB];
  #pragma unroll
  for (int p=0; p<PB; ++p){
    int el = tid + p*256, row = el>>2, ck = el&3;
    int nr = n0 + row; if (nr >= nlim) nr = nlim-1;
    bS[p]   = Bt + (size_t)nr*K + ck*8;
    bOff[p] = row*LDT + ck*8;
  }

  f4v acc[TM][TN];
  #pragma unroll
  for (int im=0; im<TM; ++im)
    #pragma unroll
    for (int in=0; in<TN; ++in) acc[im][in] = 0.f;

  u4v aR[PA]; f4v aF[PA]; u4v bR[PB];
  if (ABF16){
    #pragma unroll
    for (int p=0; p<PA; ++p) aR[p] = *(const u4v*)(aS16[p]);
  } else {
    #pragma unroll
    for (int p=0; p<PA; ++p) aF[p] = *(const f4v*)(aS32[p]);
  }
  #pragma unroll
  for (int p=0; p<PB; ++p) bR[p] = *(const u4v*)(bS[p]);

  const int KB = K >> 5;
  int cur = 0;
  for (int kb=0; kb<KB; ++kb){
    if (ABF16){
      #pragma unroll
      for (int p=0; p<PA; ++p) *(u4v*)&Al[cur][aOff[p]] = aR[p];
    } else {
      #pragma unroll
      for (int p=0; p<PA; ++p){
        uint2 pk;
        pk.x = (u32)f2bf(aF[p].x) | ((u32)f2bf(aF[p].y)<<16);
        pk.y = (u32)f2bf(aF[p].z) | ((u32)f2bf(aF[p].w)<<16);
        *(uint2*)&Al[cur][aOff[p]] = pk;
      }
    }
    #pragma unroll
    for (int p=0; p<PB; ++p) *(u4v*)&Bl[cur][bOff[p]] = bR[p];
    if (kb+1 < KB){
      const int ko = (kb+1)*32;
      if (ABF16){
        #pragma unroll
        for (int p=0; p<PA; ++p) aR[p] = *(const u4v*)(aS16[p] + ko);
      } else {
        #pragma unroll
        for (int p=0; p<PA; ++p) aF[p] = *(const f4v*)(aS32[p] + ko);
      }
      #pragma unroll
      for (int p=0; p<PB; ++p) bR[p] = *(const u4v*)(bS[p] + ko);
    }
    __syncthreads();
    s8v af[TM], bfr[TN];
    #pragma unroll
    for (int im=0; im<TM; ++im)
      af[im] = ld_frag16(&Al[cur][(wm+im*16+ln)*LDT + q*8]);
    #pragma unroll
    for (int in=0; in<TN; ++in)
      bfr[in] = ld_frag16(&Bl[cur][(wn+in*16+ln)*LDT + q*8]);
    #pragma unroll
    for (int im=0; im<TM; ++im)
      #pragma unroll
      for (int in=0; in<TN; ++in)
        acc[im][in] = mfma16(af[im], bfr[in], acc[im][in]);
    cur ^= 1;
  }

  // epilogue. C/D layout: col = lane&15, row = (lane>>4)*4 + reg
  #pragma unroll
  for (int im=0; im<TM; ++im){
    const int rbase = m0 + wm + im*16 + q*4;
    #pragma unroll
    for (int in=0; in<TN; ++in){
      const int col = n0 + wn + in*16 + ln;
      if (EPI == 0){
        #pragma unroll
        for (int r=0; r<4; ++r)
          C[(size_t)(rbase+r)*ldc + col] = acc[im][in][r];
      } else if (EPI == 1){
        float bb = bias[col];
        u16* Cb = (u16*)C;
        #pragma unroll
        for (int r=0; r<4; ++r)
          Cb[(size_t)(rbase+r)*ldc + col] = f2bf(tanhf(acc[im][in][r] + bb));
      }
    }
  }
}

// ---------------------------------------------------------------------------
// gen = exp(attn_bf @ gen_w) streamed from NATIVE gen_w [512][50000] fp32.
// BM=256 (all rows, B read exactly once), BN=64, 4 waves 2x2 (wave 128x32).
// Double-buffered LDS + prefetch distance 2 (two named reg sets).
// Also writes 1e-10 to OOV cols [50000,51000). grid 797, block 256.
// ---------------------------------------------------------------------------
__global__ __launch_bounds__(256, 3)
void gen_nat(const u16* __restrict__ A,      // attn_bf [256][512] bf16
             const float* __restrict__ W,    // gen_w [512][50000] fp32
             float* __restrict__ outp)
{
  constexpr int LDT = 40;
  __shared__ u16 Al[2][256*LDT];   // 2 x 20 KB
  __shared__ u16 Bl[2][64*LDT];    // 2 x 5 KB
  const int tid  = threadIdx.x;
  const int lane = tid & 63, wave = tid >> 6;
  const int q = lane >> 4, ln = lane & 15;
  const int wm = (wave >> 1) * 128;
  const int wn = (wave & 1) * 32;
  const int n0 = blockIdx.x * 64;

  // A staging: 4 chunks of (row = tid>>2 + p*64, 8 bf16 at ck*8)
  const int arow = tid >> 2, ack = (tid & 3) * 8;
  // B staging: thread covers k = 2*kp,2*kp+1  x  cols nw*4..+3
  const int kp = tid >> 4;          // 0..15
  const int nw = tid & 15;          // 0..15
  int bcol = n0 + nw*4; if (bcol > NVOC-4) bcol = NVOC-4;
  const float* w0 = W + (size_t)(2*kp)  *NVOC + bcol;
  const float* w1 = W + (size_t)(2*kp+1)*NVOC + bcol;
  const int bLoff = (nw*4)*LDT + kp*2;          // u16 index
  const size_t CH = (size_t)32*NVOC;            // k-chunk stride in floats

  f4v acc[8][2];
  #pragma unroll
  for (int im=0; im<8; ++im){ acc[im][0] = 0.f; acc[im][1] = 0.f; }

  u4v aA[4], aB[4];
  f4v b0A, b1A, b0B, b1B;
  // prologue: chunk 0 -> set A, chunk 1 -> set B
  #pragma unroll
  for (int p=0; p<4; ++p)
    aA[p] = *(const u4v*)(A + (size_t)(arow + p*64)*NH + ack);
  b0A = *(const f4v*)(w0);
  b1A = *(const f4v*)(w1);
  #pragma unroll
  for (int p=0; p<4; ++p)
    aB[p] = *(const u4v*)(A + (size_t)(arow + p*64)*NH + 32 + ack);
  b0B = *(const f4v*)(w0 + CH);
  b1B = *(const f4v*)(w1 + CH);

  for (int kb=0; kb<16; kb+=2){
    // ---- even chunk: commit set A -> buf0, prefetch kb+2 -> set A
    #pragma unroll
    for (int p=0; p<4; ++p) *(u4v*)&Al[0][(arow + p*64)*LDT + ack] = aA[p];
    #pragma unroll
    for (int i=0; i<4; ++i){
      u32 v = (u32)f2bf(b0A[i]) | ((u32)f2bf(b1A[i])<<16);
      *(u32*)&Bl[0][bLoff + i*LDT] = v;
    }
    if (kb+2 < 16){
      #pragma unroll
      for (int p=0; p<4; ++p)
        aA[p] = *(const u4v*)(A + (size_t)(arow + p*64)*NH + (kb+2)*32 + ack);
      b0A = *(const f4v*)(w0 + (size_t)(kb+2)*CH);
      b1A = *(const f4v*)(w1 + (size_t)(kb+2)*CH);
    }
    __syncthreads();
    {
      s8v bf0 = ld_frag16(&Bl[0][(wn + ln)*LDT + q*8]);
      s8v bf1 = ld_frag16(&Bl[0][(wn + 16 + ln)*LDT + q*8]);
      #pragma unroll
      for (int im=0; im<8; ++im){
        s8v af = ld_frag16(&Al[0][(wm + im*16 + ln)*LDT + q*8]);
        acc[im][0] = mfma16(af, bf0, acc[im][0]);
        acc[im][1] = mfma16(af, bf1, acc[im][1]);
      }
    }
    // ---- odd chunk: commit set B -> buf1, prefetch kb+3 -> set B
    #pragma unroll
    for (int p=0; p<4; ++p) *(u4v*)&Al[1][(arow + p*64)*LDT + ack] = aB[p];
    #pragma unroll
    for (int i=0; i<4; ++i){
      u32 v = (u32)f2bf(b0B[i]) | ((u32)f2bf(b1B[i])<<16);
      *(u32*)&Bl[1][bLoff + i*LDT] = v;
    }
    if (kb+3 < 16){
      #pragma unroll
      for (int p=0; p<4; ++p)
        aB[p] = *(const u4v*)(A + (size_t)(arow + p*64)*NH + (kb+3)*32 + ack);
      b0B = *(const f4v*)(w0 + (size_t)(kb+3)*CH);
      b1B = *(const f4v*)(w1 + (size_t)(kb+3)*CH);
    }
    __syncthreads();
    {
      s8v bf0 = ld_frag16(&Bl[1][(wn + ln)*LDT + q*8]);
      s8v bf1 = ld_frag16(&Bl[1][(wn + 16 + ln)*LDT + q*8]);
      #pragma unroll
      for (int im=0; im<8; ++im){
        s8v af = ld_frag16(&Al[1][(wm + im*16 + ln)*LDT + q*8]);
        acc[im][0] = mfma16(af, bf0, acc[im][0]);
        acc[im][1] = mfma16(af, bf1, acc[im][1]);
      }
    }
  }

  // epilogue: exp + store (OOV cols get 1e-10).  col = lane&15 pattern.
  #pragma unroll
  for (int im=0; im<8; ++im){
    const int rbase = wm + im*16 + q*4;
    #pragma unroll
    for (int in=0; in<2; ++in){
      const int col = n0 + wn + in*16 + ln;
      if (col < NVT){
        #pragma unroll
        for (int r=0; r<4; ++r){
          float v = (col < NVOC) ? __expf(acc[im][in][r]) : 1e-10f;
          outp[(size_t)(rbase+r)*NVT + col] = v;
        }
      }
    }
  }
}

// ---------------------------------------------------------------------------
// One LSTM step. grid 32 (j-slices of 16), block 256 = 4 waves (one per gate).
// ---------------------------------------------------------------------------
__global__ __launch_bounds__(256)
void lstm_step2(const u16* __restrict__ wrT, const float* __restrict__ xk,
                const float* __restrict__ bias, const u16* __restrict__ hb_in,
                u16* __restrict__ hb_out, float* __restrict__ c_cur,
                float* __restrict__ hidden, float* __restrict__ out_h,
                float* __restrict__ out_c, int t)
{
  const int tid = threadIdx.x, lane = tid & 63, g = tid >> 6;
  const int q = lane >> 4, ln = lane & 15;
  const int j0 = blockIdx.x * 16;

  f4v acc0 = 0.f, acc1 = 0.f;
  const u16* bp = wrT + (size_t)(g*NH + j0 + ln)*NH;
  const u16* a0 = hb_in + (size_t)ln*NH;
  const u16* a1 = hb_in + (size_t)(16+ln)*NH;
  #pragma unroll 4
  for (int kb=0; kb<16; ++kb){
    s8v bf  = ld_frag16(bp + kb*32 + q*8);
    s8v af0 = ld_frag16(a0 + kb*32 + q*8);
    s8v af1 = ld_frag16(a1 + kb*32 + q*8);
    acc0 = mfma16(af0, bf, acc0);
    acc1 = mfma16(af1, bf, acc1);
  }

  __shared__ float zs[4][32][17];
  #pragma unroll
  for (int r=0; r<4; ++r){
    zs[g][q*4+r][ln]    = acc0[r];
    zs[g][16+q*4+r][ln] = acc1[r];
  }
  __syncthreads();

  #pragma unroll
  for (int pp=0; pp<2; ++pp){
    int pair = tid + pp*256;
    int b = pair >> 4, jj = pair & 15;
    int j = j0 + jj;
    const float* xr = xk + (size_t)(b*NT+t)*2048;
    float zi = zs[0][b][jj] + xr[j]        + bias[j];
    float zf = zs[1][b][jj] + xr[NH+j]     + bias[NH+j];
    float zg = zs[2][b][jj] + xr[2*NH+j]   + bias[2*NH+j];
    float zo = zs[3][b][jj] + xr[3*NH+j]   + bias[3*NH+j];
    float c = sigm(zf)*c_cur[(size_t)b*NH+j] + sigm(zi)*tanhf(zg);
    float h = sigm(zo)*tanhf(c);
    c_cur[(size_t)b*NH+j] = c;
    hb_out[(size_t)b*NH+j] = f2bf(h);
    hidden[(size_t)(b*NT+t)*NH + j] = h;
    if (t == NT-1){ out_h[(size_t)b*NH+j] = h; out_c[(size_t)b*NH+j] = c; }
  }
}

// ---------------------------------------------------------------------------
// Attention: scores = q . enc, masked softmax over s, context; writes concat.
// ---------------------------------------------------------------------------
__global__ __launch_bounds__(1024)
void attn_ctx(const float* __restrict__ q, const float* __restrict__ enc,
              const int* __restrict__ enc_len, const float* __restrict__ hidden,
              float* __restrict__ concat)
{
  const int b = blockIdx.x;
  __shared__ float qs[NT][NENC];
  __shared__ float at[NT][NS];
  __shared__ float cred[NT][NENC];
  const int tid = threadIdx.x;
  for (int i=tid; i<NT*NENC; i+=1024) ((float*)qs)[i] = q[(size_t)b*NT*NENC + i];
  __syncthreads();
  const int len = enc_len[b];
  {
    int s = tid & 255, tg = (tid >> 8) * 2;
    const float* er = enc + ((size_t)(b*NS+s))*NENC;
    float s0 = 0.f, s1 = 0.f;
    for (int e=0; e<NENC; e+=4){
      f4v v = *(const f4v*)(er+e);
      s0 += v.x*qs[tg][e]   + v.y*qs[tg][e+1]   + v.z*qs[tg][e+2]   + v.w*qs[tg][e+3];
      s1 += v.x*qs[tg+1][e] + v.y*qs[tg+1][e+1] + v.z*qs[tg+1][e+2] + v.w*qs[tg+1][e+3];
    }
    bool m = s < len;
    at[tg][s]   = m ? s0 : -3.0e38f;
    at[tg+1][s] = m ? s1 : -3.0e38f;
  }
  __syncthreads();
  {
    int wave = tid >> 6, lane = tid & 63;
    if (wave < NT){
      float v[4]; float mx = -3.0e38f;
      #pragma unroll
      for (int i=0;i<4;++i){ v[i] = at[wave][lane+64*i]; mx = fmaxf(mx, v[i]); }
      #pragma unroll
      for (int off=1; off<64; off<<=1) mx = fmaxf(mx, __shfl_xor(mx, off, 64));
      float sum = 0.f;
      #pragma unroll
      for (int i=0;i<4;++i){ v[i] = __expf(v[i]-mx); sum += v[i]; }
      #pragma unroll
      for (int off=1; off<64; off<<=1) sum += __shfl_xor(sum, off, 64);
      float inv = 1.f/sum;
      #pragma unroll
      for (int i=0;i<4;++i) at[wave][lane+64*i] = v[i]*inv;
    }
  }
  __syncthreads();
  {
    int e = tid & 511, sh = tid >> 9;
    float cx[NT];
    #pragma unroll
    for (int t=0;t<NT;++t) cx[t] = 0.f;
    for (int si=0; si<128; ++si){
      int s = sh*128 + si;
      float v = enc[((size_t)(b*NS+s))*NENC + e];
      #pragma unroll
      for (int t=0;t<NT;++t) cx[t] += at[t][s]*v;
    }
    if (sh == 1){
      #pragma unroll
      for (int t=0;t<NT;++t) cred[t][e] = cx[t];
    }
    __syncthreads();
    if (sh == 0){
      #pragma unroll
      for (int t=0;t<NT;++t)
        concat[(size_t)(b*NT+t)*1024 + e] = cx[t] + cred[t][e];
    } else {
      #pragma unroll
      for (int t=0;t<NT;++t)
        concat[(size_t)(b*NT+t)*1024 + 512 + e] = hidden[(size_t)(b*NT+t)*NH + e];
    }
  }
}

// ---------------------------------------------------------------------------
// cs = exp(attn_out @ copy_k^T) with mask; scatter-add into extended vocab.
// grid 128 = (b, sblk).  (rowsum handled later by row_reduce_log)
// ---------------------------------------------------------------------------
__global__ __launch_bounds__(256)
void cs_scatter(const u16* __restrict__ attn_bf, const u16* __restrict__ copy_k,
                const int* __restrict__ enc_x, const int* __restrict__ enc_len,
                float* __restrict__ outp)
{
  const int b  = blockIdx.x >> 2;
  const int sb = blockIdx.x & 3;
  __shared__ u16 Al[16*520];
  const int tid = threadIdx.x;
  for (int i=tid; i<16*64; i+=256){
    int row = i >> 6, ck = i & 63;
    uint2 v0 = {0u,0u}, v1 = {0u,0u};
    if (row < NT){
      const u16* s = attn_bf + ((size_t)(b*NT+row))*NH + ck*8;
      v0 = *(const uint2*)s; v1 = *(const uint2*)(s+4);
    }
    u16* d = &Al[row*520 + ck*8];
    *(uint2*)d = v0; *(uint2*)(d+4) = v1;
  }
  __syncthreads();
  const int wave = tid >> 6, lane = tid & 63;
  const int q = lane >> 4, ln = lane & 15;
  const int s0 = sb*64 + wave*16;
  f4v acc = 0.f;
  const u16* Bg = copy_k + ((size_t)(b*NS + s0 + ln))*NH;
  for (int kb=0; kb<16; ++kb){
    s8v a  = ld_frag16(&Al[ln*520 + kb*32 + q*8]);
    s8v bb = ld_frag16(Bg + kb*32 + q*8);
    acc = mfma16(a, bb, acc);
  }
  const int s = s0 + ln;
  const int len = enc_len[b];
  const int vidx = enc_x[b*NS + s];
  const bool valid = (s < len);
  #pragma unroll
  for (int r=0; r<4; ++r){
    int t = q*4 + r;
    float e = (valid && t < NT) ? __expf(acc[r]) : 0.f;
    if (e != 0.f) atomicAdd(&outp[(size_t)(b*NT+t)*NVT + vidx], e);
  }
}

// ---------------------------------------------------------------------------
// Per-row sum over full extended vocab -> logsum[r] = log(sum).
// grid 256 (one block per output row), block 256.
// ---------------------------------------------------------------------------
__global__ __launch_bounds__(256)
void row_reduce_log(const float* __restrict__ outp, float* __restrict__ logsum)
{
  const int r = blockIdx.x;
  const int tid = threadIdx.x;
  const float* p = outp + (size_t)r*NVT;
  float sum = 0.f;
  for (int i4 = tid; i4 < 12750; i4 += 256){
    f4v v = *(const f4v*)(p + i4*4);
    sum += v.x + v.y + v.z + v.w;
  }
  #pragma unroll
  for (int off=1; off<64; off<<=1) sum += __shfl_xor(sum, off, 64);
  __shared__ float ws[4];
  if ((tid & 63) == 0) ws[tid>>6] = sum;
  __syncthreads();
  if (tid == 0) logsum[r] = __logf(ws[0]+ws[1]+ws[2]+ws[3]);
}

// ---------------------------------------------------------------------------
// out = log(total) - logsum[row]; 2D grid (f4-chunk, row)
// ---------------------------------------------------------------------------
__global__ __launch_bounds__(256)
void norm_log(float* __restrict__ outp, const float* __restrict__ logsum){
  const int i4 = blockIdx.x*256 + threadIdx.x;   // 0..12749 per row
  if (i4 >= 12750) return;
  const int r = blockIdx.y;
  const float ls = logsum[r];
  float* p = outp + (size_t)r*NVT + i4*4;
  f4v v = *(const f4v*)p;
  v.x = __logf(v.x) - ls;
  v.y = __logf(v.y) - ls;
  v.z = __logf(v.z) - ls;
  v.w = __logf(v.w) - ls;
  *(f4v*)p = v;
}

// ---------------------------------------------------------------------------
extern "C" void kernel_launch(void* const* d_in, const int* in_sizes, int n_in,
                              void* d_out, int out_size, void* d_ws, size_t ws_size,
                              hipStream_t stream)
{
  (void)in_sizes; (void)n_in; (void)out_size; (void)ws_size;
  const int*   dec_x      = (const int*)  d_in[0];
  const int*   enc_x      = (const int*)  d_in[1];
  const int*   enc_len    = (const int*)  d_in[2];
  const float* enc_output = (const float*)d_in[3];
  const float* enc_h      = (const float*)d_in[4];
  const float* enc_c      = (const float*)d_in[5];
  const float* embedding  = (const float*)d_in[8];
  const float* lstm_k     = (const float*)d_in[9];
  const float* lstm_r     = (const float*)d_in[10];
  const float* lstm_b     = (const float*)d_in[11];
  const float* attn_w     = (const float*)d_in[12];
  const float* out_w      = (const float*)d_in[13];
  const float* out_b      = (const float*)d_in[14];
  const float* gen_w      = (const float*)d_in[15];
  const float* copy_w     = (const float*)d_in[16];
  const float* copy_b     = (const float*)d_in[17];

  float* outp  = (float*)d_out;
  float* out_h = outp + (size_t)NB*NT*NVT;       // 13,056,000
  float* out_c = out_h + NB*NH;

  char* ws = (char*)d_ws;
  u16*   wrT     = (u16*)ws;    ws += (size_t)2048*NH*2;      // 2 MB
  u16*   lstmkT  = (u16*)ws;    ws += (size_t)2048*NEMB*2;    // 1 MB
  u16*   attnT   = (u16*)ws;    ws += (size_t)NENC*NH*2;      // 512 KB
  u16*   outT    = (u16*)ws;    ws += (size_t)NH*1024*2;      // 1 MB
  u16*   copyT   = (u16*)ws;    ws += (size_t)NH*NENC*2;      // 512 KB
  float* xk      = (float*)ws;  ws += (size_t)NB*NT*2048*4;   // 2 MB
  u16*   hb0     = (u16*)ws;    ws += (size_t)NB*NH*2;
  u16*   hb1     = (u16*)ws;    ws += (size_t)NB*NH*2;
  float* c_cur   = (float*)ws;  ws += (size_t)NB*NH*4;
  float* hidden  = (float*)ws;  ws += (size_t)NB*NT*NH*4;     // 512 KB
  float* qbuf    = (float*)ws;  ws += (size_t)NB*NT*NENC*4;   // 512 KB
  float* concat  = (float*)ws;  ws += (size_t)NB*NT*1024*4;   // 1 MB
  u16*   attn_bf = (u16*)ws;    ws += (size_t)NB*NT*NH*2;     // 256 KB
  u16*   copy_k  = (u16*)ws;    ws += (size_t)NB*NS*NH*2;     // 8 MB
  float* logsum  = (float*)ws;  ws += NB*NT*4;

  // ---- one-time layout conversions (bf16, [N][K]) — small weights only
  transpose_cvt<<<dim3(64,16), 256,0,stream>>>(lstm_r, wrT,    NH,  2048);
  transpose_cvt<<<dim3(64,8),  256,0,stream>>>(lstm_k, lstmkT, NEMB,2048);
  transpose_cvt<<<dim3(16,16), 256,0,stream>>>(attn_w, attnT,  NH,  NENC);
  transpose_cvt<<<dim3(16,32), 256,0,stream>>>(out_w,  outT,   1024,NH);
  transpose_cvt<<<dim3(16,16), 256,0,stream>>>(copy_w, copyT,  NENC,NH);
  cvt_bf16<<<16,256,0,stream>>>(enc_h, hb0);
  hipMemcpyAsync(c_cur, enc_c, NB*NH*4, hipMemcpyDeviceToDevice, stream);

  // copy_k = tanh(enc_output @ copy_w + copy_b) -> bf16 (M=8192, K=512, N=512)
  gemm_bt<64,128,1,false,false,false><<<dim3(4,128),256,0,stream>>>(
      enc_output, copyT, (float*)copy_k, nullptr, copy_b, nullptr, NENC, NENC, NH, NH);

  // xk = embedding[dec_x] @ lstm_k   (M=256, K=256, N=2048)
  gemm_bt<32,64,0,false,true,true><<<dim3(8,32),256,0,stream>>>(
      embedding, lstmkT, xk, dec_x, nullptr, nullptr, NEMB, NEMB, 2048, 2048);

  u16* hb[2] = {hb0, hb1};
  for (int t=0; t<NT; ++t)
    lstm_step2<<<32,256,0,stream>>>(wrT, xk, lstm_b, hb[t&1], hb[(t+1)&1],
                                    c_cur, hidden, out_h, out_c, t);

  // q = hidden @ attn_w  (M=256, K=512, N=512)
  gemm_bt<32,64,0,false,false,true><<<dim3(8,8),256,0,stream>>>(
      hidden, attnT, qbuf, nullptr, nullptr, nullptr, NH, NH, NENC, NENC);

  attn_ctx<<<32,1024,0,stream>>>(qbuf, enc_output, enc_len, hidden, concat);

  // attn_out = tanh(concat @ out_w + out_b) -> bf16  (M=256, K=1024, N=512)
  gemm_bt<32,64,1,false,false,true><<<dim3(8,8),256,0,stream>>>(
      concat, outT, (float*)attn_bf, nullptr, out_b, nullptr, 1024, 1024, NH, NH);

  // gen = exp(attn_bf @ gen_w) from native fp32 gen_w; fills OOV with 1e-10
  gen_nat<<<797,256,0,stream>>>(attn_bf, gen_w, outp);

  cs_scatter<<<128,256,0,stream>>>(attn_bf, copy_k, enc_x, enc_len, outp);
  row_reduce_log<<<NB*NT,256,0,stream>>>(outp, logsum);
  norm_log<<<dim3(50,NB*NT),256,0,stream>>>(outp, logsum);
}

// Round 5
// 451.576 us; speedup vs baseline: 1.3372x; 1.1129x over previous
//
#include <hip/hip_runtime.h>
#include <hip/hip_bf16.h>

typedef unsigned short u16;
typedef unsigned int   u32;
typedef __attribute__((ext_vector_type(4))) float f4v;
typedef __attribute__((ext_vector_type(8))) short s8v;
typedef __attribute__((ext_vector_type(4))) unsigned int u4v;

#define NB   32      // batch
#define NS   256     // src len
#define NT   8       // dec len
#define NH   512     // hidden
#define NENC 512
#define NEMB 256
#define NVOC 50000
#define NVT  51000

__device__ __forceinline__ float bf2f(u16 u){ return __uint_as_float(((u32)u)<<16); }
__device__ __forceinline__ u16 f2bf(float f){
  u32 x = __float_as_uint(f);
  return (u16)((x + 0x7fffu + ((x>>16)&1u)) >> 16);   // RNE
}
__device__ __forceinline__ s8v ld_frag16(const u16* p){
  union{ s8v v; u4v u; } t;
  t.u = *(const u4v*)p;
  return t.v;
}
__device__ __forceinline__ f4v mfma16(s8v a, s8v b, f4v c){
  return __builtin_amdgcn_mfma_f32_16x16x32_bf16(a,b,c,0,0,0);
}
__device__ __forceinline__ float sigm(float x){ return 1.f/(1.f+__expf(-x)); }

// ---------------------------------------------------------------------------
// Transpose+convert: in [K][N] fp32 -> out [N][K] bf16.  32x32 tiles via LDS.
// grid (ceil(N/32), K/32, batch), block 256.  batch advances both by K*N.
// ---------------------------------------------------------------------------
__global__ __launch_bounds__(256)
void transpose_cvt(const float* __restrict__ in, u16* __restrict__ out,
                   int K, int N)
{
  in  += (size_t)blockIdx.z * K * N;
  out += (size_t)blockIdx.z * K * N;
  __shared__ u16 tile[32*40];
  const int n0 = blockIdx.x*32, k0 = blockIdx.y*32;
  const int tid = threadIdx.x;
  {
    int r = tid>>3, c4 = tid&7;
    int c = n0 + c4*4;
    if (c+4 > N) c = N-4;
    f4v v = *(const f4v*)(in + (size_t)(k0+r)*N + c);
    uint2 p;
    p.x = (u32)f2bf(v.x) | ((u32)f2bf(v.y)<<16);
    p.y = (u32)f2bf(v.z) | ((u32)f2bf(v.w)<<16);
    *(uint2*)&tile[r*40 + c4*4] = p;
  }
  __syncthreads();
  {
    int r2 = tid>>3, kc = tid&7;
    int n = n0 + r2;
    if (n < N){
      u16 e[4];
      #pragma unroll
      for (int j=0; j<4; ++j) e[j] = tile[(kc*4+j)*40 + r2];
      *(uint2*)(out + (size_t)n*K + k0 + kc*4) = *(uint2*)e;
    }
  }
}

// ---------------------------------------------------------------------------
// fp32 -> bf16 converter (grid*256*4 elements)
// ---------------------------------------------------------------------------
__global__ __launch_bounds__(256)
void cvt_bf16(const float* __restrict__ src, u16* __restrict__ dst){
  int i = (blockIdx.x*256 + threadIdx.x) * 4;
  f4v v = *(const f4v*)(src + i);
  uint2 p;
  p.x = (u32)f2bf(v.x) | ((u32)f2bf(v.y)<<16);
  p.y = (u32)f2bf(v.z) | ((u32)f2bf(v.w)<<16);
  *(uint2*)(dst + i) = p;
}

// ---------------------------------------------------------------------------
// Tiled bf16-MFMA GEMM, B pre-transposed: C[M,N] = epi(A[M,K] @ Bt[N,K]^T)
// EPI 0: fp32   1: bf16 tanh(x+bias)   3: bf16 plain
// Pipelined K-loop: double-buffered LDS, reg-staged prefetch of tile k+1.
// ---------------------------------------------------------------------------
template<int BM, int BN, int EPI, bool ABF16, bool AGATHER, bool MXA>
__global__ __launch_bounds__(256)
void gemm_bt(const void* __restrict__ Av, const u16* __restrict__ Bt,
             float* __restrict__ C, const int* __restrict__ a_idx,
             const float* __restrict__ bias, float* __restrict__ rowsum,
             int K, int lda, int ldc, int nlim)
{
  constexpr int LDT = 40;
  constexpr int PA  = ABF16 ? BM/64 : BM/32;
  constexpr int PB  = BN/64;
  __shared__ u16 Al[2][BM*LDT];
  __shared__ u16 Bl[2][BN*LDT];
  const int tid  = threadIdx.x;
  const int lane = tid & 63;
  const int wave = tid >> 6;
  const int m0 = (MXA ? blockIdx.x : blockIdx.y) * BM;
  const int n0 = (MXA ? blockIdx.y : blockIdx.x) * BN;
  constexpr int TM = BM/32;
  constexpr int TN = BN/32;
  const int wm = (wave>>1)*(BM/2);
  const int wn = (wave&1)*(BN/2);
  const int q  = lane >> 4;
  const int ln = lane & 15;

  const u16*  aS16[PA];
  const float* aS32[PA];
  int aOff[PA];
  if (ABF16){
    const u16* Ag = (const u16*)Av;
    #pragma unroll
    for (int p=0; p<PA; ++p){
      int el = tid + p*256, row = el>>2, ck = el&3;
      aS16[p] = Ag + (size_t)(m0+row)*lda + ck*8;
      aS32[p] = nullptr;
      aOff[p] = row*LDT + ck*8;
    }
  } else {
    const float* Ag = (const float*)Av;
    #pragma unroll
    for (int p=0; p<PA; ++p){
      int el = tid + p*256, row = el>>3, ck = el&7;
      int grow = AGATHER ? a_idx[m0+row] : (m0+row);
      aS32[p] = Ag + (size_t)grow*lda + ck*4;
      aS16[p] = nullptr;
      aOff[p] = row*LDT + ck*4;
    }
  }
  const u16* bS[PB];
  int bOff[PB];
  #pragma unroll
  for (int p=0; p<PB; ++p){
    int el = tid + p*256, row = el>>2, ck = el&3;
    int nr = n0 + row; if (nr >= nlim) nr = nlim-1;
    bS[p]   = Bt + (size_t)nr*K + ck*8;
    bOff[p] = row*LDT + ck*8;
  }

  f4v acc[TM][TN];
  #pragma unroll
  for (int im=0; im<TM; ++im)
    #pragma unroll
    for (int in=0; in<TN; ++in) acc[im][in] = 0.f;

  u4v aR[PA]; f4v aF[PA]; u4v bR[PB];
  if (ABF16){
    #pragma unroll
    for (int p=0; p<PA; ++p) aR[p] = *(const u4v*)(aS16[p]);
  } else {
    #pragma unroll
    for (int p=0; p<PA; ++p) aF[p] = *(const f4v*)(aS32[p]);
  }
  #pragma unroll
  for (int p=0; p<PB; ++p) bR[p] = *(const u4v*)(bS[p]);

  const int KB = K >> 5;
  int cur = 0;
  for (int kb=0; kb<KB; ++kb){
    if (ABF16){
      #pragma unroll
      for (int p=0; p<PA; ++p) *(u4v*)&Al[cur][aOff[p]] = aR[p];
    } else {
      #pragma unroll
      for (int p=0; p<PA; ++p){
        uint2 pk;
        pk.x = (u32)f2bf(aF[p].x) | ((u32)f2bf(aF[p].y)<<16);
        pk.y = (u32)f2bf(aF[p].z) | ((u32)f2bf(aF[p].w)<<16);
        *(uint2*)&Al[cur][aOff[p]] = pk;
      }
    }
    #pragma unroll
    for (int p=0; p<PB; ++p) *(u4v*)&Bl[cur][bOff[p]] = bR[p];
    if (kb+1 < KB){
      const int ko = (kb+1)*32;
      if (ABF16){
        #pragma unroll
        for (int p=0; p<PA; ++p) aR[p] = *(const u4v*)(aS16[p] + ko);
      } else {
        #pragma unroll
        for (int p=0; p<PA; ++p) aF[p] = *(const f4v*)(aS32[p] + ko);
      }
      #pragma unroll
      for (int p=0; p<PB; ++p) bR[p] = *(const u4v*)(bS[p] + ko);
    }
    __syncthreads();
    s8v af[TM], bfr[TN];
    #pragma unroll
    for (int im=0; im<TM; ++im)
      af[im] = ld_frag16(&Al[cur][(wm+im*16+ln)*LDT + q*8]);
    #pragma unroll
    for (int in=0; in<TN; ++in)
      bfr[in] = ld_frag16(&Bl[cur][(wn+in*16+ln)*LDT + q*8]);
    #pragma unroll
    for (int im=0; im<TM; ++im)
      #pragma unroll
      for (int in=0; in<TN; ++in)
        acc[im][in] = mfma16(af[im], bfr[in], acc[im][in]);
    cur ^= 1;
  }

  // epilogue. C/D layout: col = lane&15, row = (lane>>4)*4 + reg
  #pragma unroll
  for (int im=0; im<TM; ++im){
    const int rbase = m0 + wm + im*16 + q*4;
    #pragma unroll
    for (int in=0; in<TN; ++in){
      const int col = n0 + wn + in*16 + ln;
      if (EPI == 0){
        #pragma unroll
        for (int r=0; r<4; ++r)
          C[(size_t)(rbase+r)*ldc + col] = acc[im][in][r];
      } else if (EPI == 1){
        float bb = bias[col];
        u16* Cb = (u16*)C;
        #pragma unroll
        for (int r=0; r<4; ++r)
          Cb[(size_t)(rbase+r)*ldc + col] = f2bf(tanhf(acc[im][in][r] + bb));
      } else if (EPI == 3){
        u16* Cb = (u16*)C;
        #pragma unroll
        for (int r=0; r<4; ++r)
          Cb[(size_t)(rbase+r)*ldc + col] = f2bf(acc[im][in][r]);
      }
    }
  }
}

// ---------------------------------------------------------------------------
// gen = exp(attn_bf @ gen_w) streamed from NATIVE gen_w [512][50000] fp32.
// BM=256, BN=64, 4 waves 2x2. dbuf LDS + prefetch distance 2.
// OOV cols get 1e-10. grid 797, block 256.
// ---------------------------------------------------------------------------
__global__ __launch_bounds__(256, 3)
void gen_nat(const u16* __restrict__ A,      // attn_bf [256][512] bf16
             const float* __restrict__ W,    // gen_w [512][50000] fp32
             float* __restrict__ outp)
{
  constexpr int LDT = 40;
  __shared__ u16 Al[2][256*LDT];
  __shared__ u16 Bl[2][64*LDT];
  const int tid  = threadIdx.x;
  const int lane = tid & 63, wave = tid >> 6;
  const int q = lane >> 4, ln = lane & 15;
  const int wm = (wave >> 1) * 128;
  const int wn = (wave & 1) * 32;
  const int n0 = blockIdx.x * 64;

  const int arow = tid >> 2, ack = (tid & 3) * 8;
  const int kp = tid >> 4;
  const int nw = tid & 15;
  int bcol = n0 + nw*4; if (bcol > NVOC-4) bcol = NVOC-4;
  const float* w0 = W + (size_t)(2*kp)  *NVOC + bcol;
  const float* w1 = W + (size_t)(2*kp+1)*NVOC + bcol;
  const int bLoff = (nw*4)*LDT + kp*2;
  const size_t CH = (size_t)32*NVOC;

  f4v acc[8][2];
  #pragma unroll
  for (int im=0; im<8; ++im){ acc[im][0] = 0.f; acc[im][1] = 0.f; }

  u4v aA[4], aB[4];
  f4v b0A, b1A, b0B, b1B;
  #pragma unroll
  for (int p=0; p<4; ++p)
    aA[p] = *(const u4v*)(A + (size_t)(arow + p*64)*NH + ack);
  b0A = *(const f4v*)(w0);
  b1A = *(const f4v*)(w1);
  #pragma unroll
  for (int p=0; p<4; ++p)
    aB[p] = *(const u4v*)(A + (size_t)(arow + p*64)*NH + 32 + ack);
  b0B = *(const f4v*)(w0 + CH);
  b1B = *(const f4v*)(w1 + CH);

  for (int kb=0; kb<16; kb+=2){
    #pragma unroll
    for (int p=0; p<4; ++p) *(u4v*)&Al[0][(arow + p*64)*LDT + ack] = aA[p];
    #pragma unroll
    for (int i=0; i<4; ++i){
      u32 v = (u32)f2bf(b0A[i]) | ((u32)f2bf(b1A[i])<<16);
      *(u32*)&Bl[0][bLoff + i*LDT] = v;
    }
    if (kb+2 < 16){
      #pragma unroll
      for (int p=0; p<4; ++p)
        aA[p] = *(const u4v*)(A + (size_t)(arow + p*64)*NH + (kb+2)*32 + ack);
      b0A = *(const f4v*)(w0 + (size_t)(kb+2)*CH);
      b1A = *(const f4v*)(w1 + (size_t)(kb+2)*CH);
    }
    __syncthreads();
    {
      s8v bf0 = ld_frag16(&Bl[0][(wn + ln)*LDT + q*8]);
      s8v bf1 = ld_frag16(&Bl[0][(wn + 16 + ln)*LDT + q*8]);
      #pragma unroll
      for (int im=0; im<8; ++im){
        s8v af = ld_frag16(&Al[0][(wm + im*16 + ln)*LDT + q*8]);
        acc[im][0] = mfma16(af, bf0, acc[im][0]);
        acc[im][1] = mfma16(af, bf1, acc[im][1]);
      }
    }
    #pragma unroll
    for (int p=0; p<4; ++p) *(u4v*)&Al[1][(arow + p*64)*LDT + ack] = aB[p];
    #pragma unroll
    for (int i=0; i<4; ++i){
      u32 v = (u32)f2bf(b0B[i]) | ((u32)f2bf(b1B[i])<<16);
      *(u32*)&Bl[1][bLoff + i*LDT] = v;
    }
    if (kb+3 < 16){
      #pragma unroll
      for (int p=0; p<4; ++p)
        aB[p] = *(const u4v*)(A + (size_t)(arow + p*64)*NH + (kb+3)*32 + ack);
      b0B = *(const f4v*)(w0 + (size_t)(kb+3)*CH);
      b1B = *(const f4v*)(w1 + (size_t)(kb+3)*CH);
    }
    __syncthreads();
    {
      s8v bf0 = ld_frag16(&Bl[1][(wn + ln)*LDT + q*8]);
      s8v bf1 = ld_frag16(&Bl[1][(wn + 16 + ln)*LDT + q*8]);
      #pragma unroll
      for (int im=0; im<8; ++im){
        s8v af = ld_frag16(&Al[1][(wm + im*16 + ln)*LDT + q*8]);
        acc[im][0] = mfma16(af, bf0, acc[im][0]);
        acc[im][1] = mfma16(af, bf1, acc[im][1]);
      }
    }
  }

  #pragma unroll
  for (int im=0; im<8; ++im){
    const int rbase = wm + im*16 + q*4;
    #pragma unroll
    for (int in=0; in<2; ++in){
      const int col = n0 + wn + in*16 + ln;
      if (col < NVT){
        #pragma unroll
        for (int r=0; r<4; ++r){
          float v = (col < NVOC) ? __expf(acc[im][in][r]) : 1e-10f;
          outp[(size_t)(rbase+r)*NVT + col] = v;
        }
      }
    }
  }
}

// ---------------------------------------------------------------------------
// One LSTM step. grid 32 (j-slices of 16), block 256 = 4 waves (one per gate).
// h written directly into concat[...][512+j] (fp32) + hb_out (bf16).
// ---------------------------------------------------------------------------
__global__ __launch_bounds__(256)
void lstm_step2(const u16* __restrict__ wrT, const float* __restrict__ xk,
                const float* __restrict__ bias, const u16* __restrict__ hb_in,
                u16* __restrict__ hb_out, float* __restrict__ c_cur,
                float* __restrict__ concat, float* __restrict__ out_h,
                float* __restrict__ out_c, int t)
{
  const int tid = threadIdx.x, lane = tid & 63, g = tid >> 6;
  const int q = lane >> 4, ln = lane & 15;
  const int j0 = blockIdx.x * 16;

  f4v acc0 = 0.f, acc1 = 0.f;
  const u16* bp = wrT + (size_t)(g*NH + j0 + ln)*NH;
  const u16* a0 = hb_in + (size_t)ln*NH;
  const u16* a1 = hb_in + (size_t)(16+ln)*NH;
  #pragma unroll 4
  for (int kb=0; kb<16; ++kb){
    s8v bf  = ld_frag16(bp + kb*32 + q*8);
    s8v af0 = ld_frag16(a0 + kb*32 + q*8);
    s8v af1 = ld_frag16(a1 + kb*32 + q*8);
    acc0 = mfma16(af0, bf, acc0);
    acc1 = mfma16(af1, bf, acc1);
  }

  __shared__ float zs[4][32][17];
  #pragma unroll
  for (int r=0; r<4; ++r){
    zs[g][q*4+r][ln]    = acc0[r];
    zs[g][16+q*4+r][ln] = acc1[r];
  }
  __syncthreads();

  #pragma unroll
  for (int pp=0; pp<2; ++pp){
    int pair = tid + pp*256;
    int b = pair >> 4, jj = pair & 15;
    int j = j0 + jj;
    const float* xr = xk + (size_t)(b*NT+t)*2048;
    float zi = zs[0][b][jj] + xr[j]        + bias[j];
    float zf = zs[1][b][jj] + xr[NH+j]     + bias[NH+j];
    float zg = zs[2][b][jj] + xr[2*NH+j]   + bias[2*NH+j];
    float zo = zs[3][b][jj] + xr[3*NH+j]   + bias[3*NH+j];
    float c = sigm(zf)*c_cur[(size_t)b*NH+j] + sigm(zi)*tanhf(zg);
    float h = sigm(zo)*tanhf(c);
    c_cur[(size_t)b*NH+j] = c;
    hb_out[(size_t)b*NH+j] = f2bf(h);
    concat[(size_t)(b*NT+t)*1024 + 512 + j] = h;
    if (t == NT-1){ out_h[(size_t)b*NH+j] = h; out_c[(size_t)b*NH+j] = c; }
  }
}

// ---------------------------------------------------------------------------
// Attention scores + softmax via MFMA.  grid 32 (b), 512 thr (8 waves).
// scores[t][s] = q_bf[t] . enc_bf[s] (K=512); mask; per-wave softmax (t=wave);
// P written fp32 to at_p [B][8][256].
// ---------------------------------------------------------------------------
__global__ __launch_bounds__(512)
void attn_sm(const u16* __restrict__ q_bf,   // [256][512] bf16
             const u16* __restrict__ enc_bf, // [32][256][512] bf16
             const int* __restrict__ enc_len,
             float* __restrict__ at_p)       // [32][8][256] fp32
{
  const int b = blockIdx.x;
  __shared__ u16 Al[16*520];
  __shared__ float at[8][256];
  const int tid = threadIdx.x;
  // stage q rows (8 valid + 8 zero-pad) as A-tile [16][512]
  for (int i=tid; i<16*64; i+=512){
    int row = i >> 6, ck = i & 63;
    uint2 v0 = {0u,0u}, v1 = {0u,0u};
    if (row < NT){
      const u16* s = q_bf + ((size_t)(b*NT+row))*NH + ck*8;
      v0 = *(const uint2*)s; v1 = *(const uint2*)(s+4);
    }
    u16* d = &Al[row*520 + ck*8];
    *(uint2*)d = v0; *(uint2*)(d+4) = v1;
  }
  __syncthreads();
  const int wave = tid >> 6, lane = tid & 63;
  const int q = lane >> 4, ln = lane & 15;
  const int len = enc_len[b];
  // scores: wave handles s in [wave*32, wave*32+32)
  f4v acc0 = 0.f, acc1 = 0.f;
  const u16* Bg0 = enc_bf + ((size_t)(b*NS + wave*32 + ln))*NENC;
  const u16* Bg1 = enc_bf + ((size_t)(b*NS + wave*32 + 16 + ln))*NENC;
  for (int kb=0; kb<16; ++kb){
    s8v a  = ld_frag16(&Al[ln*520 + kb*32 + q*8]);
    s8v b0 = ld_frag16(Bg0 + kb*32 + q*8);
    s8v b1 = ld_frag16(Bg1 + kb*32 + q*8);
    acc0 = mfma16(a, b0, acc0);
    acc1 = mfma16(a, b1, acc1);
  }
  {
    const int s0 = wave*32 + ln, s1 = s0 + 16;
    const bool m0 = s0 < len, m1 = s1 < len;
    #pragma unroll
    for (int r=0; r<4; ++r){
      int t = q*4 + r;
      if (t < NT){
        at[t][s0] = m0 ? acc0[r] : -3.0e38f;
        at[t][s1] = m1 ? acc1[r] : -3.0e38f;
      }
    }
  }
  __syncthreads();
  // softmax: wave w handles t=w (8 waves, 8 t-rows)
  {
    float v[4]; float mx = -3.0e38f;
    #pragma unroll
    for (int i=0;i<4;++i){ v[i] = at[wave][lane+64*i]; mx = fmaxf(mx, v[i]); }
    #pragma unroll
    for (int off=1; off<64; off<<=1) mx = fmaxf(mx, __shfl_xor(mx, off, 64));
    float sum = 0.f;
    #pragma unroll
    for (int i=0;i<4;++i){ v[i] = __expf(v[i]-mx); sum += v[i]; }
    #pragma unroll
    for (int off=1; off<64; off<<=1) sum += __shfl_xor(sum, off, 64);
    float inv = 1.f/sum;
    #pragma unroll
    for (int i=0;i<4;++i)
      at_p[((size_t)(b*NT+wave))*NS + lane+64*i] = v[i]*inv;
  }
}

// ---------------------------------------------------------------------------
// context = P @ enc (via encT_bf) -> concat[r][0:512].
// grid (32 b, 8 eb), 256 thr (4 waves x 16 e).  K=256 (s).
// ---------------------------------------------------------------------------
__global__ __launch_bounds__(256)
void attn_ctx2(const float* __restrict__ at_p,   // [32][8][256] fp32
               const u16* __restrict__ encT_bf,  // [32][512][256] bf16
               float* __restrict__ concat)       // [256][1024]
{
  const int b = blockIdx.x, eb = blockIdx.y;
  __shared__ u16 Al[16*264];
  const int tid = threadIdx.x;
  // stage P rows (8 valid + 8 zero) as A-tile [16][256] bf16
  for (int i=tid; i<16*64; i+=256){
    int row = i >> 6, c4 = i & 63;
    uint2 pk = {0u,0u};
    if (row < NT){
      f4v v = *(const f4v*)(at_p + ((size_t)(b*NT+row))*NS + c4*4);
      pk.x = (u32)f2bf(v.x) | ((u32)f2bf(v.y)<<16);
      pk.y = (u32)f2bf(v.z) | ((u32)f2bf(v.w)<<16);
    }
    *(uint2*)&Al[row*264 + c4*4] = pk;
  }
  __syncthreads();
  const int wave = tid >> 6, lane = tid & 63;
  const int q = lane >> 4, ln = lane & 15;
  const int e = eb*64 + wave*16 + ln;
  f4v acc = 0.f;
  const u16* Bg = encT_bf + ((size_t)(b*NENC + e))*NS;
  for (int kb=0; kb<8; ++kb){
    s8v a  = ld_frag16(&Al[ln*264 + kb*32 + q*8]);
    s8v bb = ld_frag16(Bg + kb*32 + q*8);
    acc = mfma16(a, bb, acc);
  }
  #pragma unroll
  for (int r=0; r<4; ++r){
    int t = q*4 + r;
    if (t < NT) concat[(size_t)(b*NT+t)*1024 + e] = acc[r];
  }
}

// ---------------------------------------------------------------------------
// cs = exp(attn_out @ copy_k^T) with mask; scatter-add into extended vocab.
// grid 128 = (b, sblk).
// ---------------------------------------------------------------------------
__global__ __launch_bounds__(256)
void cs_scatter(const u16* __restrict__ attn_bf, const u16* __restrict__ copy_k,
                const int* __restrict__ enc_x, const int* __restrict__ enc_len,
                float* __restrict__ outp)
{
  const int b  = blockIdx.x >> 2;
  const int sb = blockIdx.x & 3;
  __shared__ u16 Al[16*520];
  const int tid = threadIdx.x;
  for (int i=tid; i<16*64; i+=256){
    int row = i >> 6, ck = i & 63;
    uint2 v0 = {0u,0u}, v1 = {0u,0u};
    if (row < NT){
      const u16* s = attn_bf + ((size_t)(b*NT+row))*NH + ck*8;
      v0 = *(const uint2*)s; v1 = *(const uint2*)(s+4);
    }
    u16* d = &Al[row*520 + ck*8];
    *(uint2*)d = v0; *(uint2*)(d+4) = v1;
  }
  __syncthreads();
  const int wave = tid >> 6, lane = tid & 63;
  const int q = lane >> 4, ln = lane & 15;
  const int s0 = sb*64 + wave*16;
  f4v acc = 0.f;
  const u16* Bg = copy_k + ((size_t)(b*NS + s0 + ln))*NH;
  for (int kb=0; kb<16; ++kb){
    s8v a  = ld_frag16(&Al[ln*520 + kb*32 + q*8]);
    s8v bb = ld_frag16(Bg + kb*32 + q*8);
    acc = mfma16(a, bb, acc);
  }
  const int s = s0 + ln;
  const int len = enc_len[b];
  const int vidx = enc_x[b*NS + s];
  const bool valid = (s < len);
  #pragma unroll
  for (int r=0; r<4; ++r){
    int t = q*4 + r;
    float e = (valid && t < NT) ? __expf(acc[r]) : 0.f;
    if (e != 0.f) atomicAdd(&outp[(size_t)(b*NT+t)*NVT + vidx], e);
  }
}

// ---------------------------------------------------------------------------
// Per-row sum over full extended vocab -> logsum[r] = log(sum). grid 256.
// ---------------------------------------------------------------------------
__global__ __launch_bounds__(256)
void row_reduce_log(const float* __restrict__ outp, float* __restrict__ logsum)
{
  const int r = blockIdx.x;
  const int tid = threadIdx.x;
  const float* p = outp + (size_t)r*NVT;
  float sum = 0.f;
  for (int i4 = tid; i4 < 12750; i4 += 256){
    f4v v = *(const f4v*)(p + i4*4);
    sum += v.x + v.y + v.z + v.w;
  }
  #pragma unroll
  for (int off=1; off<64; off<<=1) sum += __shfl_xor(sum, off, 64);
  __shared__ float ws[4];
  if ((tid & 63) == 0) ws[tid>>6] = sum;
  __syncthreads();
  if (tid == 0) logsum[r] = __logf(ws[0]+ws[1]+ws[2]+ws[3]);
}

// ---------------------------------------------------------------------------
// out = log(total) - logsum[row]; 2D grid (f4-chunk, row)
// ---------------------------------------------------------------------------
__global__ __launch_bounds__(256)
void norm_log(float* __restrict__ outp, const float* __restrict__ logsum){
  const int i4 = blockIdx.x*256 + threadIdx.x;   // 0..12749 per row
  if (i4 >= 12750) return;
  const int r = blockIdx.y;
  const float ls = logsum[r];
  float* p = outp + (size_t)r*NVT + i4*4;
  f4v v = *(const f4v*)p;
  v.x = __logf(v.x) - ls;
  v.y = __logf(v.y) - ls;
  v.z = __logf(v.z) - ls;
  v.w = __logf(v.w) - ls;
  *(f4v*)p = v;
}

// ---------------------------------------------------------------------------
extern "C" void kernel_launch(void* const* d_in, const int* in_sizes, int n_in,
                              void* d_out, int out_size, void* d_ws, size_t ws_size,
                              hipStream_t stream)
{
  (void)in_sizes; (void)n_in; (void)out_size; (void)ws_size;
  const int*   dec_x      = (const int*)  d_in[0];
  const int*   enc_x      = (const int*)  d_in[1];
  const int*   enc_len    = (const int*)  d_in[2];
  const float* enc_output = (const float*)d_in[3];
  const float* enc_h      = (const float*)d_in[4];
  const float* enc_c      = (const float*)d_in[5];
  const float* embedding  = (const float*)d_in[8];
  const float* lstm_k     = (const float*)d_in[9];
  const float* lstm_r     = (const float*)d_in[10];
  const float* lstm_b     = (const float*)d_in[11];
  const float* attn_w     = (const float*)d_in[12];
  const float* out_w      = (const float*)d_in[13];
  const float* out_b      = (const float*)d_in[14];
  const float* gen_w      = (const float*)d_in[15];
  const float* copy_w     = (const float*)d_in[16];
  const float* copy_b     = (const float*)d_in[17];

  float* outp  = (float*)d_out;
  float* out_h = outp + (size_t)NB*NT*NVT;       // 13,056,000
  float* out_c = out_h + NB*NH;

  char* ws = (char*)d_ws;
  u16*   wrT     = (u16*)ws;    ws += (size_t)2048*NH*2;      // 2 MB
  u16*   lstmkT  = (u16*)ws;    ws += (size_t)2048*NEMB*2;    // 1 MB
  u16*   attnT   = (u16*)ws;    ws += (size_t)NENC*NH*2;      // 512 KB
  u16*   outT    = (u16*)ws;    ws += (size_t)NH*1024*2;      // 1 MB
  u16*   copyT   = (u16*)ws;    ws += (size_t)NH*NENC*2;      // 512 KB
  float* xk      = (float*)ws;  ws += (size_t)NB*NT*2048*4;   // 2 MB
  u16*   hb0     = (u16*)ws;    ws += (size_t)NB*NH*2;
  u16*   hb1     = (u16*)ws;    ws += (size_t)NB*NH*2;
  float* c_cur   = (float*)ws;  ws += (size_t)NB*NH*4;
  u16*   q_bf    = (u16*)ws;    ws += (size_t)NB*NT*NENC*2;   // 256 KB
  float* at_p    = (float*)ws;  ws += (size_t)NB*NT*NS*4;     // 256 KB
  float* concat  = (float*)ws;  ws += (size_t)NB*NT*1024*4;   // 1 MB
  u16*   attn_bf = (u16*)ws;    ws += (size_t)NB*NT*NH*2;     // 256 KB
  u16*   copy_k  = (u16*)ws;    ws += (size_t)NB*NS*NH*2;     // 8 MB
  u16*   enc_bf  = (u16*)ws;    ws += (size_t)NB*NS*NENC*2;   // 8 MB
  u16*   encT_bf = (u16*)ws;    ws += (size_t)NB*NENC*NS*2;   // 8 MB
  float* logsum  = (float*)ws;  ws += NB*NT*4;

  // ---- one-time conversions
  cvt_bf16<<<4096,256,0,stream>>>(enc_output, enc_bf);            // enc -> bf16
  transpose_cvt<<<dim3(16,8,32),256,0,stream>>>(enc_output, encT_bf, NS, NENC);
  transpose_cvt<<<dim3(64,16), 256,0,stream>>>(lstm_r, wrT,    NH,  2048);
  transpose_cvt<<<dim3(64,8),  256,0,stream>>>(lstm_k, lstmkT, NEMB,2048);
  transpose_cvt<<<dim3(16,16), 256,0,stream>>>(attn_w, attnT,  NH,  NENC);
  transpose_cvt<<<dim3(16,32), 256,0,stream>>>(out_w,  outT,   1024,NH);
  transpose_cvt<<<dim3(16,16), 256,0,stream>>>(copy_w, copyT,  NENC,NH);
  cvt_bf16<<<16,256,0,stream>>>(enc_h, hb0);
  hipMemcpyAsync(c_cur, enc_c, NB*NH*4, hipMemcpyDeviceToDevice, stream);

  // copy_k = tanh(enc_bf @ copy_w + copy_b) -> bf16 (M=8192, K=512, N=512)
  gemm_bt<64,128,1,true,false,false><<<dim3(4,128),256,0,stream>>>(
      enc_bf, copyT, (float*)copy_k, nullptr, copy_b, nullptr, NENC, NENC, NH, NH);

  // xk = embedding[dec_x] @ lstm_k   (M=256, K=256, N=2048)
  gemm_bt<32,64,0,false,true,true><<<dim3(8,32),256,0,stream>>>(
      embedding, lstmkT, xk, dec_x, nullptr, nullptr, NEMB, NEMB, 2048, 2048);

  u16* hb[2] = {hb0, hb1};
  for (int t=0; t<NT; ++t)
    lstm_step2<<<32,256,0,stream>>>(wrT, xk, lstm_b, hb[t&1], hb[(t+1)&1],
                                    c_cur, concat, out_h, out_c, t);

  // q_bf = hidden @ attn_w  (hidden = concat[:,512:], lda=1024) -> bf16
  gemm_bt<32,64,3,false,false,true><<<dim3(8,8),256,0,stream>>>(
      concat + 512, attnT, (float*)q_bf, nullptr, nullptr, nullptr, NH, 1024, NENC, NENC);

  attn_sm<<<32,512,0,stream>>>(q_bf, enc_bf, enc_len, at_p);
  attn_ctx2<<<dim3(32,8),256,0,stream>>>(at_p, encT_bf, concat);

  // attn_out = tanh(concat @ out_w + out_b) -> bf16  (M=256, K=1024, N=512)
  gemm_bt<32,64,1,false,false,true><<<dim3(8,8),256,0,stream>>>(
      concat, outT, (float*)attn_bf, nullptr, out_b, nullptr, 1024, 1024, NH, NH);

  // gen = exp(attn_bf @ gen_w) from native fp32 gen_w; fills OOV with 1e-10
  gen_nat<<<797,256,0,stream>>>(attn_bf, gen_w, outp);

  cs_scatter<<<128,256,0,stream>>>(attn_bf, copy_k, enc_x, enc_len, outp);
  row_reduce_log<<<NB*NT,256,0,stream>>>(outp, logsum);
  norm_log<<<dim3(50,NB*NT),256,0,stream>>>(outp, logsum);
}